// Round 1
// baseline (809.312 us; speedup 1.0000x reference)
//
#include <hip/hip_runtime.h>
#include <math.h>

// ---------------------------------------------------------------------------
// Problem constants (shapes from reference): D=128 feature dim, ED=32 edge dim
// ---------------------------------------------------------------------------

// Precompute wa = We @ a_e for both layers (each 32 floats).  ee @ a_e ==
// edge_attr @ (We @ a_e), so the [E,128] edge embedding is never materialized.
__global__ __launch_bounds__(64) void prep_wa(
    const float* __restrict__ We1, const float* __restrict__ ae1,
    const float* __restrict__ We2, const float* __restrict__ ae2,
    float* __restrict__ wa /* 64 floats: wa1[0:32], wa2[32:64] */)
{
    int t = threadIdx.x;
    const float* We = (t < 32) ? We1 : We2;
    const float* ae = (t < 32) ? ae1 : ae2;
    int r = t & 31;
    float s = 0.f;
    for (int c = 0; c < 128; c++) s += We[r*128 + c] * ae[c];
    wa[t] = s;
}

// ---------------------------------------------------------------------------
// Node GEMM: XL = X @ W  (N x 128 @ 128 x 128), fused per-row dots with
// a_src / a_dst.  32 rows per 256-thread block, 4x4 outputs per thread.
// W staged in LDS in two 64-row halves to stay under 64KB/workgroup LDS.
// ---------------------------------------------------------------------------
__global__ __launch_bounds__(256) void gemm_node(
    const float* __restrict__ X, const float* __restrict__ W,
    const float* __restrict__ asrc, const float* __restrict__ adst,
    float* __restrict__ XL, float* __restrict__ als, float* __restrict__ ald,
    int nrows)
{
    __shared__ float Wl[64 * 128];     // 32 KB (half of W at a time)
    __shared__ float Xs[32 * 132];     // 16.5 KB, padded stride 132
    int t = threadIdx.x;
    int row0 = blockIdx.x * 32;
    int nr = min(32, nrows - row0);

    // stage X rows (coalesced float4)
    for (int i = t; i < nr * 32; i += 256) {
        int r = i >> 5, cc = i & 31;
        float4 v = ((const float4*)(X + (size_t)(row0 + r) * 128))[cc];
        *(float4*)(Xs + r * 132 + cc * 4) = v;
    }

    int tr = t >> 5;   // 0..7 -> rows tr*4 .. tr*4+3
    int tc = t & 31;   // cols tc*4 .. tc*4+3
    float acc[4][4];
#pragma unroll
    for (int i = 0; i < 4; i++)
#pragma unroll
        for (int j = 0; j < 4; j++) acc[i][j] = 0.f;

    const float4* W4 = (const float4*)W;
    float4* Wl4 = (float4*)Wl;

    for (int kt = 0; kt < 128; kt += 64) {
        __syncthreads();
        // stage 64 rows of W: 8192 floats = 2048 float4
#pragma unroll
        for (int i = 0; i < 8; i++)
            Wl4[t + 256 * i] = W4[kt * 32 + t + 256 * i];
        __syncthreads();

        for (int k = 0; k < 64; k += 4) {
            float xk[4][4];
#pragma unroll
            for (int i = 0; i < 4; i++) {
                float4 v = *(const float4*)(Xs + (tr * 4 + i) * 132 + kt + k);
                xk[i][0] = v.x; xk[i][1] = v.y; xk[i][2] = v.z; xk[i][3] = v.w;
            }
#pragma unroll
            for (int kk = 0; kk < 4; kk++) {
                float4 w = *(const float4*)(Wl + (k + kk) * 128 + tc * 4);
#pragma unroll
                for (int i = 0; i < 4; i++) {
                    float xs = xk[i][kk];
                    acc[i][0] += xs * w.x; acc[i][1] += xs * w.y;
                    acc[i][2] += xs * w.z; acc[i][3] += xs * w.w;
                }
            }
        }
    }

    // write XL
#pragma unroll
    for (int i = 0; i < 4; i++) {
        int r = tr * 4 + i;
        if (r < nr) {
            float4 v = make_float4(acc[i][0], acc[i][1], acc[i][2], acc[i][3]);
            *(float4*)(XL + (size_t)(row0 + r) * 128 + tc * 4) = v;
        }
    }

    // fused attention-logit dots: als = xl . a_src, ald = xl . a_dst
    float a_s[4], a_d[4];
#pragma unroll
    for (int j = 0; j < 4; j++) { a_s[j] = asrc[tc*4 + j]; a_d[j] = adst[tc*4 + j]; }
#pragma unroll
    for (int i = 0; i < 4; i++) {
        float ps = acc[i][0]*a_s[0] + acc[i][1]*a_s[1] + acc[i][2]*a_s[2] + acc[i][3]*a_s[3];
        float pd = acc[i][0]*a_d[0] + acc[i][1]*a_d[1] + acc[i][2]*a_d[2] + acc[i][3]*a_d[3];
#pragma unroll
        for (int o = 16; o >= 1; o >>= 1) {
            ps += __shfl_down(ps, o, 32);
            pd += __shfl_down(pd, o, 32);
        }
        if (tc == 0) {
            int r = tr * 4 + i;
            if (r < nr) { als[row0 + r] = ps; ald[row0 + r] = pd; }
        }
    }
}

// ---------------------------------------------------------------------------
// Per-edge attention logits: e = leaky_relu(als[src] + ald[dst] + ea . wa)
// ---------------------------------------------------------------------------
__global__ __launch_bounds__(256) void edge_logits(
    const float* __restrict__ ea, const int* __restrict__ srcv, const int* __restrict__ dstv,
    const float* __restrict__ als, const float* __restrict__ ald,
    const float* __restrict__ wa, float* __restrict__ elog, int E)
{
    int j = blockIdx.x * 256 + threadIdx.x;
    if (j >= E) return;
    const float4* e4 = (const float4*)(ea + (size_t)j * 32);
    float s = 0.f;
#pragma unroll
    for (int i = 0; i < 8; i++) {
        float4 v = e4[i];
        float4 w = ((const float4*)wa)[i];
        s += v.x*w.x + v.y*w.y + v.z*w.z + v.w*w.w;
    }
    s += als[srcv[j]] + ald[dstv[j]];
    elog[j] = (s >= 0.f) ? s : 0.2f * s;
}

// ---------------------------------------------------------------------------
// CSR-by-dst construction (edge_index identical across both layers)
// ---------------------------------------------------------------------------
__global__ __launch_bounds__(256) void count_edges(
    const int* __restrict__ dstv, int* __restrict__ counts, int E)
{
    int j = blockIdx.x * 256 + threadIdx.x;
    if (j < E) atomicAdd(&counts[dstv[j]], 1);
}

__global__ __launch_bounds__(256) void scan_offsets(
    const int* __restrict__ counts, int* __restrict__ offs, int* __restrict__ cursor, int n)
{
    __shared__ int part[256];
    int t = threadIdx.x;
    int chunk = (n + 255) >> 8;
    int lo = t * chunk, hi = min(lo + chunk, n);
    int s = 0;
    for (int i = lo; i < hi; i++) s += counts[i];
    part[t] = s; __syncthreads();
    for (int o = 1; o < 256; o <<= 1) {
        int v = (t >= o) ? part[t - o] : 0;
        __syncthreads();
        part[t] += v;
        __syncthreads();
    }
    int run = (t == 0) ? 0 : part[t - 1];
    for (int i = lo; i < hi; i++) { offs[i] = run; cursor[i] = run; run += counts[i]; }
    if (t == 255) offs[n] = run;
}

__global__ __launch_bounds__(256) void scatter_edges(
    const int* __restrict__ dstv, int* __restrict__ cursor, int* __restrict__ csr, int E)
{
    int j = blockIdx.x * 256 + threadIdx.x;
    if (j < E) { int p = atomicAdd(&cursor[dstv[j]], 1); csr[p] = j; }
}

// ---------------------------------------------------------------------------
// Per-dst-node: segment softmax over incoming edges + weighted gather of
// xl[src] rows + bias, fused with LayerNorm.  One 128-thread block per node,
// one channel per thread.  No float atomics.
// ---------------------------------------------------------------------------
__global__ __launch_bounds__(128) void aggregate_ln(
    const float* __restrict__ XL, const float* __restrict__ elog,
    const int* __restrict__ offs, const int* __restrict__ csr, const int* __restrict__ srcv,
    const float* __restrict__ bias, const float* __restrict__ gamma, const float* __restrict__ beta,
    float* __restrict__ Xout)
{
    int node = blockIdx.x;
    int t = threadIdx.x;
    __shared__ float wsh[128];
    __shared__ int   ssh[128];
    __shared__ float red[128];
    int lo = offs[node], hi = offs[node + 1];
    int deg = hi - lo;

    // segment max
    float mloc = -3.402823466e38f;
    for (int j = t; j < deg; j += 128) mloc = fmaxf(mloc, elog[csr[lo + j]]);
    red[t] = mloc; __syncthreads();
#pragma unroll
    for (int o = 64; o >= 1; o >>= 1) { if (t < o) red[t] = fmaxf(red[t], red[t + o]); __syncthreads(); }
    float m = red[0];
    __syncthreads();

    // exp weights + weighted gather (chunked; deg ~12 so usually one chunk)
    float acc = 0.f, sloc = 0.f;
    for (int base = 0; base < deg; base += 128) {
        int cnt = min(128, deg - base);
        if (t < cnt) {
            int eid = csr[lo + base + t];
            float w = __expf(elog[eid] - m);
            wsh[t] = w; ssh[t] = srcv[eid]; sloc += w;
        }
        __syncthreads();
        for (int j = 0; j < cnt; j++)
            acc += wsh[j] * XL[(size_t)ssh[j] * 128 + t];
        __syncthreads();
    }
    red[t] = sloc; __syncthreads();
#pragma unroll
    for (int o = 64; o >= 1; o >>= 1) { if (t < o) red[t] += red[t + o]; __syncthreads(); }
    float ssum = red[0]; __syncthreads();

    float y = acc / (ssum + 1e-16f) + bias[t];

    // fused LayerNorm over the 128 channels
    red[t] = y; __syncthreads();
#pragma unroll
    for (int o = 64; o >= 1; o >>= 1) { if (t < o) red[t] += red[t + o]; __syncthreads(); }
    float mean = red[0] * (1.f / 128.f); __syncthreads();
    float d = y - mean;
    red[t] = d * d; __syncthreads();
#pragma unroll
    for (int o = 64; o >= 1; o >>= 1) { if (t < o) red[t] += red[t + o]; __syncthreads(); }
    float var = red[0] * (1.f / 128.f);
    Xout[(size_t)node * 128 + t] = d * rsqrtf(var + 1e-5f) * gamma[t] + beta[t];
}

// ---------------------------------------------------------------------------
// Global mean pool (batch is sorted) + final linear + LN + ReLU.
// One 128-thread block per graph.
// ---------------------------------------------------------------------------
__global__ __launch_bounds__(128) void pool_final(
    const float* __restrict__ X4, const int* __restrict__ batch,
    const float* __restrict__ Wl, const float* __restrict__ bl,
    const float* __restrict__ gl, const float* __restrict__ bel,
    float* __restrict__ out, int n)
{
    int g = blockIdx.x, t = threadIdx.x;
    // lower_bound(batch, g) and lower_bound(batch, g+1)
    int lo = 0, hi = n;
    while (lo < hi) { int mid = (lo + hi) >> 1; if (batch[mid] < g) lo = mid + 1; else hi = mid; }
    int s = lo;
    hi = n;
    while (lo < hi) { int mid = (lo + hi) >> 1; if (batch[mid] < g + 1) lo = mid + 1; else hi = mid; }
    int e = lo;

    float acc = 0.f;
    for (int r = s; r < e; r++) acc += X4[(size_t)r * 128 + t];
    float cntf = (float)(e - s);
    float pooled = acc / fmaxf(cntf, 1.f);

    __shared__ float ps[128];
    __shared__ float red[128];
    ps[t] = pooled; __syncthreads();

    float y = bl[t];
    for (int k = 0; k < 128; k++) y += ps[k] * Wl[k * 128 + t];

    red[t] = y; __syncthreads();
#pragma unroll
    for (int o = 64; o >= 1; o >>= 1) { if (t < o) red[t] += red[t + o]; __syncthreads(); }
    float mean = red[0] * (1.f / 128.f); __syncthreads();
    float d = y - mean;
    red[t] = d * d; __syncthreads();
#pragma unroll
    for (int o = 64; o >= 1; o >>= 1) { if (t < o) red[t] += red[t + o]; __syncthreads(); }
    float var = red[0] * (1.f / 128.f);
    float z = d * rsqrtf(var + 1e-5f) * gl[t] + bel[t];
    out[g * 128 + t] = fmaxf(z, 0.f);
}

// ---------------------------------------------------------------------------

extern "C" void kernel_launch(void* const* d_in, const int* in_sizes, int n_in,
                              void* d_out, int out_size, void* d_ws, size_t ws_size,
                              hipStream_t stream)
{
    const float* x    = (const float*)d_in[0];
    const float* ea   = (const float*)d_in[1];
    const float* W1   = (const float*)d_in[2];
    const float* as1  = (const float*)d_in[3];
    const float* ad1  = (const float*)d_in[4];
    const float* We1  = (const float*)d_in[5];
    const float* ae1  = (const float*)d_in[6];
    const float* b1   = (const float*)d_in[7];
    const float* g1   = (const float*)d_in[8];
    const float* be1  = (const float*)d_in[9];
    const float* W2   = (const float*)d_in[10];
    const float* as2  = (const float*)d_in[11];
    const float* ad2  = (const float*)d_in[12];
    const float* We2  = (const float*)d_in[13];
    const float* ae2  = (const float*)d_in[14];
    const float* b2   = (const float*)d_in[15];
    const float* g2   = (const float*)d_in[16];
    const float* be2  = (const float*)d_in[17];
    const float* Wlin = (const float*)d_in[18];
    const float* bl   = (const float*)d_in[19];
    const float* gl   = (const float*)d_in[20];
    const float* bel  = (const float*)d_in[21];
    const int*   ei   = (const int*)d_in[22];
    const int*   batch= (const int*)d_in[23];
    float* out = (float*)d_out;

    int N = in_sizes[0] / 128;
    int E = in_sizes[1] / 32;
    int G = out_size / 128;
    const int* srcv = ei;
    const int* dstv = ei + E;

    // workspace layout (16B-aligned bump allocator)
    char* wsb = (char*)d_ws;
    size_t off = 0;
    auto alloc = [&](size_t bytes) -> void* {
        void* p = wsb + off;
        off += (bytes + 15) & ~(size_t)15;
        return p;
    };
    float* XL     = (float*)alloc((size_t)N * 128 * 4);
    float* XA     = (float*)alloc((size_t)N * 128 * 4);
    float* elog   = (float*)alloc((size_t)E * 4);
    float* als    = (float*)alloc((size_t)N * 4);
    float* ald    = (float*)alloc((size_t)N * 4);
    float* wa     = (float*)alloc(64 * 4);
    int*   counts = (int*)alloc((size_t)N * 4);
    int*   offs   = (int*)alloc((size_t)(N + 1) * 4);
    int*   cursor = (int*)alloc((size_t)N * 4);
    int*   csr    = (int*)alloc((size_t)E * 4);

    int egrid = (E + 255) / 256;
    int ggrid = (N + 31) / 32;

    // CSR build (shared by both layers)
    hipMemsetAsync(counts, 0, (size_t)N * 4, stream);
    prep_wa<<<1, 64, 0, stream>>>(We1, ae1, We2, ae2, wa);
    count_edges<<<egrid, 256, 0, stream>>>(dstv, counts, E);
    scan_offsets<<<1, 256, 0, stream>>>(counts, offs, cursor, N);
    scatter_edges<<<egrid, 256, 0, stream>>>(dstv, cursor, csr, E);

    // layer 1
    gemm_node<<<ggrid, 256, 0, stream>>>(x, W1, as1, ad1, XL, als, ald, N);
    edge_logits<<<egrid, 256, 0, stream>>>(ea, srcv, dstv, als, ald, wa, elog, E);
    aggregate_ln<<<N, 128, 0, stream>>>(XL, elog, offs, csr, srcv, b1, g1, be1, XA);

    // layer 2
    gemm_node<<<ggrid, 256, 0, stream>>>(XA, W2, as2, ad2, XL, als, ald, N);
    edge_logits<<<egrid, 256, 0, stream>>>(ea, srcv, dstv, als, ald, wa + 32, elog, E);
    aggregate_ln<<<N, 128, 0, stream>>>(XL, elog, offs, csr, srcv, b2, g2, be2, XA);

    // pool + head
    pool_final<<<G, 128, 0, stream>>>(XA, batch, Wlin, bl, gl, bel, out, N);
}

// Round 2
// 599.218 us; speedup vs baseline: 1.3506x; 1.3506x over previous
//
#include <hip/hip_runtime.h>
#include <math.h>

// ---------------------------------------------------------------------------
// Problem shapes: N nodes, D=128 feature dim, ED=32 edge dim, G graphs.
// ---------------------------------------------------------------------------

// Precompute wa = We @ a_e for both layers (each 32 floats).  ee @ a_e ==
// edge_attr @ (We @ a_e), so the [E,128] edge embedding is never materialized.
__global__ __launch_bounds__(64) void prep_wa(
    const float* __restrict__ We1, const float* __restrict__ ae1,
    const float* __restrict__ We2, const float* __restrict__ ae2,
    float* __restrict__ wa /* 64 floats: wa1[0:32], wa2[32:64] */)
{
    int t = threadIdx.x;
    const float* We = (t < 32) ? We1 : We2;
    const float* ae = (t < 32) ? ae1 : ae2;
    int r = t & 31;
    float s = 0.f;
    for (int c = 0; c < 128; c++) s += We[r*128 + c] * ae[c];
    wa[t] = s;
}

// One pass over edge_attr (77 MB) computing BOTH layers' edge dots.
__global__ __launch_bounds__(256) void edge_dots(
    const float* __restrict__ ea, const float* __restrict__ wa,
    float* __restrict__ edot1, float* __restrict__ edot2, int E)
{
    int j = blockIdx.x * 256 + threadIdx.x;
    if (j >= E) return;
    const float4* e4 = (const float4*)(ea + (size_t)j * 32);
    float s1 = 0.f, s2 = 0.f;
#pragma unroll
    for (int i = 0; i < 8; i++) {
        float4 v = e4[i];
        float4 w1 = ((const float4*)wa)[i];
        float4 w2 = ((const float4*)(wa + 32))[i];
        s1 += v.x*w1.x + v.y*w1.y + v.z*w1.z + v.w*w1.w;
        s2 += v.x*w2.x + v.y*w2.y + v.z*w2.z + v.w*w2.w;
    }
    edot1[j] = s1; edot2[j] = s2;
}

// ---------------------------------------------------------------------------
// Node GEMM: XL = X @ W  (N x 128 @ 128 x 128), fused per-row dots with
// a_src / a_dst.  32 rows per 256-thread block, 4x4 outputs per thread.
// ---------------------------------------------------------------------------
__global__ __launch_bounds__(256) void gemm_node(
    const float* __restrict__ X, const float* __restrict__ W,
    const float* __restrict__ asrc, const float* __restrict__ adst,
    float* __restrict__ XL, float* __restrict__ als, float* __restrict__ ald,
    int nrows)
{
    __shared__ float Wl[64 * 128];     // 32 KB (half of W at a time)
    __shared__ float Xs[32 * 132];     // 16.5 KB, padded stride 132
    int t = threadIdx.x;
    int row0 = blockIdx.x * 32;
    int nr = min(32, nrows - row0);

    for (int i = t; i < nr * 32; i += 256) {
        int r = i >> 5, cc = i & 31;
        float4 v = ((const float4*)(X + (size_t)(row0 + r) * 128))[cc];
        *(float4*)(Xs + r * 132 + cc * 4) = v;
    }

    int tr = t >> 5;
    int tc = t & 31;
    float acc[4][4];
#pragma unroll
    for (int i = 0; i < 4; i++)
#pragma unroll
        for (int j = 0; j < 4; j++) acc[i][j] = 0.f;

    const float4* W4 = (const float4*)W;
    float4* Wl4 = (float4*)Wl;

    for (int kt = 0; kt < 128; kt += 64) {
        __syncthreads();
#pragma unroll
        for (int i = 0; i < 8; i++)
            Wl4[t + 256 * i] = W4[kt * 32 + t + 256 * i];
        __syncthreads();

        for (int k = 0; k < 64; k += 4) {
            float xk[4][4];
#pragma unroll
            for (int i = 0; i < 4; i++) {
                float4 v = *(const float4*)(Xs + (tr * 4 + i) * 132 + kt + k);
                xk[i][0] = v.x; xk[i][1] = v.y; xk[i][2] = v.z; xk[i][3] = v.w;
            }
#pragma unroll
            for (int kk = 0; kk < 4; kk++) {
                float4 w = *(const float4*)(Wl + (k + kk) * 128 + tc * 4);
#pragma unroll
                for (int i = 0; i < 4; i++) {
                    float xs = xk[i][kk];
                    acc[i][0] += xs * w.x; acc[i][1] += xs * w.y;
                    acc[i][2] += xs * w.z; acc[i][3] += xs * w.w;
                }
            }
        }
    }

#pragma unroll
    for (int i = 0; i < 4; i++) {
        int r = tr * 4 + i;
        if (r < nr) {
            float4 v = make_float4(acc[i][0], acc[i][1], acc[i][2], acc[i][3]);
            *(float4*)(XL + (size_t)(row0 + r) * 128 + tc * 4) = v;
        }
    }

    float a_s[4], a_d[4];
#pragma unroll
    for (int j = 0; j < 4; j++) { a_s[j] = asrc[tc*4 + j]; a_d[j] = adst[tc*4 + j]; }
#pragma unroll
    for (int i = 0; i < 4; i++) {
        float ps = acc[i][0]*a_s[0] + acc[i][1]*a_s[1] + acc[i][2]*a_s[2] + acc[i][3]*a_s[3];
        float pd = acc[i][0]*a_d[0] + acc[i][1]*a_d[1] + acc[i][2]*a_d[2] + acc[i][3]*a_d[3];
#pragma unroll
        for (int o = 16; o >= 1; o >>= 1) {
            ps += __shfl_down(ps, o, 32);
            pd += __shfl_down(pd, o, 32);
        }
        if (tc == 0) {
            int r = tr * 4 + i;
            if (r < nr) { als[row0 + r] = ps; ald[row0 + r] = pd; }
        }
    }
}

// ---------------------------------------------------------------------------
// Per-edge logits from precomputed edge dot: e = lrelu(als[src]+ald[dst]+edot)
// ---------------------------------------------------------------------------
__global__ __launch_bounds__(256) void edge_logits(
    const float* __restrict__ edot, const int* __restrict__ srcv, const int* __restrict__ dstv,
    const float* __restrict__ als, const float* __restrict__ ald,
    float* __restrict__ elog, int E)
{
    int j = blockIdx.x * 256 + threadIdx.x;
    if (j >= E) return;
    float s = edot[j] + als[srcv[j]] + ald[dstv[j]];
    elog[j] = (s >= 0.f) ? s : 0.2f * s;
}

// ---------------------------------------------------------------------------
// CSR-by-dst construction (edge_index identical across both layers)
// ---------------------------------------------------------------------------
__global__ __launch_bounds__(256) void count_edges(
    const int* __restrict__ dstv, int* __restrict__ counts, int E)
{
    int j = blockIdx.x * 256 + threadIdx.x;
    if (j < E) atomicAdd(&counts[dstv[j]], 1);
}

__global__ __launch_bounds__(256) void scan_offsets(
    const int* __restrict__ counts, int* __restrict__ offs, int* __restrict__ cursor, int n)
{
    __shared__ int part[256];
    int t = threadIdx.x;
    int chunk = (n + 255) >> 8;
    int lo = t * chunk, hi = min(lo + chunk, n);
    int s = 0;
    for (int i = lo; i < hi; i++) s += counts[i];
    part[t] = s; __syncthreads();
    for (int o = 1; o < 256; o <<= 1) {
        int v = (t >= o) ? part[t - o] : 0;
        __syncthreads();
        part[t] += v;
        __syncthreads();
    }
    int run = (t == 0) ? 0 : part[t - 1];
    for (int i = lo; i < hi; i++) { offs[i] = run; cursor[i] = run; run += counts[i]; }
    if (t == 255) offs[n] = run;
}

__global__ __launch_bounds__(256) void scatter_edges(
    const int* __restrict__ dstv, int* __restrict__ cursor, int* __restrict__ csr, int E)
{
    int j = blockIdx.x * 256 + threadIdx.x;
    if (j < E) { int p = atomicAdd(&cursor[dstv[j]], 1); csr[p] = j; }
}

// ---------------------------------------------------------------------------
// Wave-synchronous per-dst-node segment softmax + weighted gather + bias + LN.
// One node per 64-lane WAVE (4 nodes / 256-thread block).  Each lane owns
// channels {lane, lane+64}.  All reductions via __shfl_xor; edge weights
// broadcast via __shfl.  Zero __syncthreads, zero LDS.
// ---------------------------------------------------------------------------
__global__ __launch_bounds__(256) void aggregate_ln(
    const float* __restrict__ XL, const float* __restrict__ elog,
    const int* __restrict__ offs, const int* __restrict__ csr, const int* __restrict__ srcv,
    const float* __restrict__ bias, const float* __restrict__ gamma, const float* __restrict__ beta,
    float* __restrict__ Xout, int N)
{
    int node = blockIdx.x * 4 + (threadIdx.x >> 6);
    if (node >= N) return;
    int lane = threadIdx.x & 63;
    int lo = offs[node], hi = offs[node + 1];
    int deg = hi - lo;

    // segment max (wave reduce)
    float mloc = -3.402823466e38f;
    for (int j = lane; j < deg; j += 64) mloc = fmaxf(mloc, elog[csr[lo + j]]);
#pragma unroll
    for (int o = 32; o >= 1; o >>= 1) mloc = fmaxf(mloc, __shfl_xor(mloc, o));
    float m = mloc;

    // exp weights + weighted gather, 64 edges per chunk
    float acc0 = 0.f, acc1 = 0.f, ssum = 0.f;
    for (int base = 0; base < deg; base += 64) {
        int cnt = min(64, deg - base);
        float w = 0.f; int sidx = 0;
        if (lane < cnt) {
            int eid = csr[lo + base + lane];
            w = __expf(elog[eid] - m);
            sidx = srcv[eid];
        }
        float wl = w;
#pragma unroll
        for (int o = 32; o >= 1; o >>= 1) wl += __shfl_xor(wl, o);
        ssum += wl;
        for (int j = 0; j < cnt; j++) {
            float wj = __shfl(w, j);
            int   sj = __shfl(sidx, j);
            const float* row = XL + (size_t)sj * 128;
            acc0 += wj * row[lane];
            acc1 += wj * row[lane + 64];
        }
    }

    float inv = 1.f / (ssum + 1e-16f);
    float y0 = acc0 * inv + bias[lane];
    float y1 = acc1 * inv + bias[lane + 64];

    // fused LayerNorm over the 128 channels (2 per lane)
    float s = y0 + y1;
#pragma unroll
    for (int o = 32; o >= 1; o >>= 1) s += __shfl_xor(s, o);
    float mean = s * (1.f / 128.f);
    float d0 = y0 - mean, d1 = y1 - mean;
    float v = d0 * d0 + d1 * d1;
#pragma unroll
    for (int o = 32; o >= 1; o >>= 1) v += __shfl_xor(v, o);
    float r = rsqrtf(v * (1.f / 128.f) + 1e-5f);
    float* orow = Xout + (size_t)node * 128;
    orow[lane]      = d0 * r * gamma[lane]      + beta[lane];
    orow[lane + 64] = d1 * r * gamma[lane + 64] + beta[lane + 64];
}

// ---------------------------------------------------------------------------
// Pooling phase 1: batch is sorted, so each block walks a contiguous chunk of
// nodes, run-length accumulates per graph, and emits one atomicAdd per
// (graph-run, channel).  782 blocks -> full occupancy.
// ---------------------------------------------------------------------------
__global__ __launch_bounds__(128) void pool_partial(
    const float* __restrict__ X4, const int* __restrict__ batch,
    float* __restrict__ pooled, int n)
{
    int chunk0 = blockIdx.x * 64;
    if (chunk0 >= n) return;
    int t = threadIdx.x;
    int end = min(chunk0 + 64, n);
    float acc = 0.f;
    int gcur = batch[chunk0];
    for (int r = chunk0; r < end; r++) {
        int g = batch[r];
        if (g != gcur) {
            atomicAdd(&pooled[gcur * 128 + t], acc);
            acc = 0.f; gcur = g;
        }
        acc += X4[(size_t)r * 128 + t];
    }
    atomicAdd(&pooled[gcur * 128 + t], acc);
}

// Pooling phase 2: per-graph mean + final linear + LN + ReLU.
__global__ __launch_bounds__(128) void pool_head(
    const float* __restrict__ pooled, const int* __restrict__ batch,
    const float* __restrict__ Wl, const float* __restrict__ bl,
    const float* __restrict__ gl, const float* __restrict__ bel,
    float* __restrict__ out, int n)
{
    int g = blockIdx.x, t = threadIdx.x;
    // node count for graph g via binary search (batch sorted)
    int lo = 0, hi = n;
    while (lo < hi) { int mid = (lo + hi) >> 1; if (batch[mid] < g) lo = mid + 1; else hi = mid; }
    int s = lo;
    hi = n;
    while (lo < hi) { int mid = (lo + hi) >> 1; if (batch[mid] < g + 1) lo = mid + 1; else hi = mid; }
    float cntf = (float)(lo - s);

    __shared__ float ps[128];
    __shared__ float red[128];
    ps[t] = pooled[g * 128 + t] / fmaxf(cntf, 1.f);
    __syncthreads();

    float y = bl[t];
    for (int k = 0; k < 128; k++) y += ps[k] * Wl[k * 128 + t];

    red[t] = y; __syncthreads();
#pragma unroll
    for (int o = 64; o >= 1; o >>= 1) { if (t < o) red[t] += red[t + o]; __syncthreads(); }
    float mean = red[0] * (1.f / 128.f); __syncthreads();
    float d = y - mean;
    red[t] = d * d; __syncthreads();
#pragma unroll
    for (int o = 64; o >= 1; o >>= 1) { if (t < o) red[t] += red[t + o]; __syncthreads(); }
    float var = red[0] * (1.f / 128.f);
    float z = d * rsqrtf(var + 1e-5f) * gl[t] + bel[t];
    out[g * 128 + t] = fmaxf(z, 0.f);
}

// ---------------------------------------------------------------------------

extern "C" void kernel_launch(void* const* d_in, const int* in_sizes, int n_in,
                              void* d_out, int out_size, void* d_ws, size_t ws_size,
                              hipStream_t stream)
{
    const float* x    = (const float*)d_in[0];
    const float* ea   = (const float*)d_in[1];
    const float* W1   = (const float*)d_in[2];
    const float* as1  = (const float*)d_in[3];
    const float* ad1  = (const float*)d_in[4];
    const float* We1  = (const float*)d_in[5];
    const float* ae1  = (const float*)d_in[6];
    const float* b1   = (const float*)d_in[7];
    const float* g1   = (const float*)d_in[8];
    const float* be1  = (const float*)d_in[9];
    const float* W2   = (const float*)d_in[10];
    const float* as2  = (const float*)d_in[11];
    const float* ad2  = (const float*)d_in[12];
    const float* We2  = (const float*)d_in[13];
    const float* ae2  = (const float*)d_in[14];
    const float* b2   = (const float*)d_in[15];
    const float* g2   = (const float*)d_in[16];
    const float* be2  = (const float*)d_in[17];
    const float* Wlin = (const float*)d_in[18];
    const float* bl   = (const float*)d_in[19];
    const float* gl   = (const float*)d_in[20];
    const float* bel  = (const float*)d_in[21];
    const int*   ei   = (const int*)d_in[22];
    const int*   batch= (const int*)d_in[23];
    float* out = (float*)d_out;

    int N = in_sizes[0] / 128;
    int E = in_sizes[1] / 32;
    int G = out_size / 128;
    const int* srcv = ei;
    const int* dstv = ei + E;

    char* wsb = (char*)d_ws;
    size_t off = 0;
    auto alloc = [&](size_t bytes) -> void* {
        void* p = wsb + off;
        off += (bytes + 15) & ~(size_t)15;
        return p;
    };
    float* XL     = (float*)alloc((size_t)N * 128 * 4);
    float* XA     = (float*)alloc((size_t)N * 128 * 4);
    float* elog   = (float*)alloc((size_t)E * 4);
    float* edot1  = (float*)alloc((size_t)E * 4);
    float* edot2  = (float*)alloc((size_t)E * 4);
    float* als    = (float*)alloc((size_t)N * 4);
    float* ald    = (float*)alloc((size_t)N * 4);
    float* wa     = (float*)alloc(64 * 4);
    float* pooled = (float*)alloc((size_t)G * 128 * 4);
    int*   counts = (int*)alloc((size_t)N * 4);
    int*   offs   = (int*)alloc((size_t)(N + 1) * 4);
    int*   cursor = (int*)alloc((size_t)N * 4);
    int*   csr    = (int*)alloc((size_t)E * 4);

    int egrid = (E + 255) / 256;
    int ggrid = (N + 31) / 32;
    int agrid = (N + 3) / 4;
    int pgrid = (N + 63) / 64;

    // CSR build + edge dots (shared by both layers)
    hipMemsetAsync(counts, 0, (size_t)N * 4, stream);
    hipMemsetAsync(pooled, 0, (size_t)G * 128 * 4, stream);
    prep_wa<<<1, 64, 0, stream>>>(We1, ae1, We2, ae2, wa);
    edge_dots<<<egrid, 256, 0, stream>>>(ea, wa, edot1, edot2, E);
    count_edges<<<egrid, 256, 0, stream>>>(dstv, counts, E);
    scan_offsets<<<1, 256, 0, stream>>>(counts, offs, cursor, N);
    scatter_edges<<<egrid, 256, 0, stream>>>(dstv, cursor, csr, E);

    // layer 1
    gemm_node<<<ggrid, 256, 0, stream>>>(x, W1, as1, ad1, XL, als, ald, N);
    edge_logits<<<egrid, 256, 0, stream>>>(edot1, srcv, dstv, als, ald, elog, E);
    aggregate_ln<<<agrid, 256, 0, stream>>>(XL, elog, offs, csr, srcv, b1, g1, be1, XA, N);

    // layer 2
    gemm_node<<<ggrid, 256, 0, stream>>>(XA, W2, as2, ad2, XL, als, ald, N);
    edge_logits<<<egrid, 256, 0, stream>>>(edot2, srcv, dstv, als, ald, elog, E);
    aggregate_ln<<<agrid, 256, 0, stream>>>(XL, elog, offs, csr, srcv, b2, g2, be2, XA, N);

    // pool + head
    pool_partial<<<pgrid, 128, 0, stream>>>(XA, batch, pooled, N);
    pool_head<<<G, 128, 0, stream>>>(pooled, batch, Wlin, bl, gl, bel, out, N);
}

// Round 3
// 491.317 us; speedup vs baseline: 1.6472x; 1.2196x over previous
//
#include <hip/hip_runtime.h>
#include <math.h>

// ---------------------------------------------------------------------------
// Problem shapes: N nodes, D=128 feature dim, ED=32 edge dim, G graphs.
// ---------------------------------------------------------------------------

// Precompute wa = We @ a_e for both layers (each 32 floats).  ee @ a_e ==
// edge_attr @ (We @ a_e), so the [E,128] edge embedding is never materialized.
__global__ __launch_bounds__(64) void prep_wa(
    const float* __restrict__ We1, const float* __restrict__ ae1,
    const float* __restrict__ We2, const float* __restrict__ ae2,
    float* __restrict__ wa /* 64 floats: wa1[0:32], wa2[32:64] */)
{
    int t = threadIdx.x;
    const float* We = (t < 32) ? We1 : We2;
    const float* ae = (t < 32) ? ae1 : ae2;
    int r = t & 31;
    float s = 0.f;
    for (int c = 0; c < 128; c++) s += We[r*128 + c] * ae[c];
    wa[t] = s;
}

// One pass over edge_attr (77 MB) computing BOTH layers' edge dots.
__global__ __launch_bounds__(256) void edge_dots(
    const float* __restrict__ ea, const float* __restrict__ wa,
    float* __restrict__ edot1, float* __restrict__ edot2, int E)
{
    int j = blockIdx.x * 256 + threadIdx.x;
    if (j >= E) return;
    const float4* e4 = (const float4*)(ea + (size_t)j * 32);
    float s1 = 0.f, s2 = 0.f;
#pragma unroll
    for (int i = 0; i < 8; i++) {
        float4 v = e4[i];
        float4 w1 = ((const float4*)wa)[i];
        float4 w2 = ((const float4*)(wa + 32))[i];
        s1 += v.x*w1.x + v.y*w1.y + v.z*w1.z + v.w*w1.w;
        s2 += v.x*w2.x + v.y*w2.y + v.z*w2.z + v.w*w2.w;
    }
    edot1[j] = s1; edot2[j] = s2;
}

// ---------------------------------------------------------------------------
// Node GEMM: XL = X @ W  (N x 128 @ 128 x 128), fused per-row dots with
// a_src / a_dst.  32 rows per 256-thread block, 4x4 outputs per thread.
// ---------------------------------------------------------------------------
__global__ __launch_bounds__(256) void gemm_node(
    const float* __restrict__ X, const float* __restrict__ W,
    const float* __restrict__ asrc, const float* __restrict__ adst,
    float* __restrict__ XL, float* __restrict__ als, float* __restrict__ ald,
    int nrows)
{
    __shared__ float Wl[64 * 128];     // 32 KB (half of W at a time)
    __shared__ float Xs[32 * 132];     // 16.5 KB, padded stride 132
    int t = threadIdx.x;
    int row0 = blockIdx.x * 32;
    int nr = min(32, nrows - row0);

    for (int i = t; i < nr * 32; i += 256) {
        int r = i >> 5, cc = i & 31;
        float4 v = ((const float4*)(X + (size_t)(row0 + r) * 128))[cc];
        *(float4*)(Xs + r * 132 + cc * 4) = v;
    }

    int tr = t >> 5;
    int tc = t & 31;
    float acc[4][4];
#pragma unroll
    for (int i = 0; i < 4; i++)
#pragma unroll
        for (int j = 0; j < 4; j++) acc[i][j] = 0.f;

    const float4* W4 = (const float4*)W;
    float4* Wl4 = (float4*)Wl;

    for (int kt = 0; kt < 128; kt += 64) {
        __syncthreads();
#pragma unroll
        for (int i = 0; i < 8; i++)
            Wl4[t + 256 * i] = W4[kt * 32 + t + 256 * i];
        __syncthreads();

        for (int k = 0; k < 64; k += 4) {
            float xk[4][4];
#pragma unroll
            for (int i = 0; i < 4; i++) {
                float4 v = *(const float4*)(Xs + (tr * 4 + i) * 132 + kt + k);
                xk[i][0] = v.x; xk[i][1] = v.y; xk[i][2] = v.z; xk[i][3] = v.w;
            }
#pragma unroll
            for (int kk = 0; kk < 4; kk++) {
                float4 w = *(const float4*)(Wl + (k + kk) * 128 + tc * 4);
#pragma unroll
                for (int i = 0; i < 4; i++) {
                    float xs = xk[i][kk];
                    acc[i][0] += xs * w.x; acc[i][1] += xs * w.y;
                    acc[i][2] += xs * w.z; acc[i][3] += xs * w.w;
                }
            }
        }
    }

#pragma unroll
    for (int i = 0; i < 4; i++) {
        int r = tr * 4 + i;
        if (r < nr) {
            float4 v = make_float4(acc[i][0], acc[i][1], acc[i][2], acc[i][3]);
            *(float4*)(XL + (size_t)(row0 + r) * 128 + tc * 4) = v;
        }
    }

    float a_s[4], a_d[4];
#pragma unroll
    for (int j = 0; j < 4; j++) { a_s[j] = asrc[tc*4 + j]; a_d[j] = adst[tc*4 + j]; }
#pragma unroll
    for (int i = 0; i < 4; i++) {
        float ps = acc[i][0]*a_s[0] + acc[i][1]*a_s[1] + acc[i][2]*a_s[2] + acc[i][3]*a_s[3];
        float pd = acc[i][0]*a_d[0] + acc[i][1]*a_d[1] + acc[i][2]*a_d[2] + acc[i][3]*a_d[3];
#pragma unroll
        for (int o = 16; o >= 1; o >>= 1) {
            ps += __shfl_down(ps, o, 32);
            pd += __shfl_down(pd, o, 32);
        }
        if (tc == 0) {
            int r = tr * 4 + i;
            if (r < nr) { als[row0 + r] = ps; ald[row0 + r] = pd; }
        }
    }
}

// ---------------------------------------------------------------------------
// Per-edge logits from precomputed edge dot: e = lrelu(als[src]+ald[dst]+edot)
// ---------------------------------------------------------------------------
__global__ __launch_bounds__(256) void edge_logits(
    const float* __restrict__ edot, const int* __restrict__ srcv, const int* __restrict__ dstv,
    const float* __restrict__ als, const float* __restrict__ ald,
    float* __restrict__ elog, int E)
{
    int j = blockIdx.x * 256 + threadIdx.x;
    if (j >= E) return;
    float s = edot[j] + als[srcv[j]] + ald[dstv[j]];
    elog[j] = (s >= 0.f) ? s : 0.2f * s;
}

// ---------------------------------------------------------------------------
// CSR-by-dst construction (edge_index identical across both layers)
// ---------------------------------------------------------------------------
__global__ __launch_bounds__(256) void count_edges(
    const int* __restrict__ dstv, int* __restrict__ counts, int E)
{
    int j = blockIdx.x * 256 + threadIdx.x;
    if (j < E) atomicAdd(&counts[dstv[j]], 1);
}

// Hierarchical exclusive scan: 1024 counts per block.
// scan_local: per-block exclusive prefixes + block totals.
__global__ __launch_bounds__(256) void scan_local(
    const int* __restrict__ counts, int* __restrict__ local,
    int* __restrict__ bsums, int n)
{
    __shared__ int tmp[256];
    int b = blockIdx.x, t = threadIdx.x;
    int base = b * 1024 + t * 4;
    int v0 = 0, v1 = 0, v2 = 0, v3 = 0;
    if (base + 3 < n) {
        const int4 c4 = *(const int4*)(counts + base);
        v0 = c4.x; v1 = c4.y; v2 = c4.z; v3 = c4.w;
    } else {
        if (base + 0 < n) v0 = counts[base + 0];
        if (base + 1 < n) v1 = counts[base + 1];
        if (base + 2 < n) v2 = counts[base + 2];
        if (base + 3 < n) v3 = counts[base + 3];
    }
    tmp[t] = v0 + v1 + v2 + v3; __syncthreads();
    for (int o = 1; o < 256; o <<= 1) {
        int x = (t >= o) ? tmp[t - o] : 0;
        __syncthreads();
        tmp[t] += x;
        __syncthreads();
    }
    int run = (t == 0) ? 0 : tmp[t - 1];
    if (base + 0 < n) { local[base + 0] = run; run += v0; }
    if (base + 1 < n) { local[base + 1] = run; run += v1; }
    if (base + 2 < n) { local[base + 2] = run; run += v2; }
    if (base + 3 < n) { local[base + 3] = run; }
    if (t == 255) bsums[b] = tmp[255];
}

// scan_bsums: single block, exclusive scan of block totals in place (nb<=256).
__global__ __launch_bounds__(256) void scan_bsums(int* __restrict__ bsums, int nb)
{
    __shared__ int tmp[256];
    int t = threadIdx.x;
    tmp[t] = (t < nb) ? bsums[t] : 0; __syncthreads();
    for (int o = 1; o < 256; o <<= 1) {
        int x = (t >= o) ? tmp[t - o] : 0;
        __syncthreads();
        tmp[t] += x;
        __syncthreads();
    }
    if (t < nb) bsums[t] = (t == 0) ? 0 : tmp[t - 1];
}

// scan_add: offs[i] = cursor[i] = local[i] + bsums[i/1024]; offs[n] = E.
__global__ __launch_bounds__(256) void scan_add(
    const int* __restrict__ local, const int* __restrict__ bsums,
    int* __restrict__ offs, int* __restrict__ cursor, int n, int E)
{
    int i = blockIdx.x * 256 + threadIdx.x;
    if (i < n) {
        int v = local[i] + bsums[i >> 10];
        offs[i] = v; cursor[i] = v;
    }
    if (i == 0) offs[n] = E;
}

__global__ __launch_bounds__(256) void scatter_edges(
    const int* __restrict__ dstv, int* __restrict__ cursor, int* __restrict__ csr, int E)
{
    int j = blockIdx.x * 256 + threadIdx.x;
    if (j < E) { int p = atomicAdd(&cursor[dstv[j]], 1); csr[p] = j; }
}

// ---------------------------------------------------------------------------
// Wave-synchronous per-dst-node segment softmax + weighted gather + bias + LN.
// One node per 64-lane WAVE (4 nodes / 256-thread block).  Each lane owns
// channels {lane, lane+64}.  All reductions via __shfl_xor; edge weights
// broadcast via __shfl.  Zero __syncthreads, zero LDS.
// ---------------------------------------------------------------------------
__global__ __launch_bounds__(256) void aggregate_ln(
    const float* __restrict__ XL, const float* __restrict__ elog,
    const int* __restrict__ offs, const int* __restrict__ csr, const int* __restrict__ srcv,
    const float* __restrict__ bias, const float* __restrict__ gamma, const float* __restrict__ beta,
    float* __restrict__ Xout, int N)
{
    int node = blockIdx.x * 4 + (threadIdx.x >> 6);
    if (node >= N) return;
    int lane = threadIdx.x & 63;
    int lo = offs[node], hi = offs[node + 1];
    int deg = hi - lo;

    // segment max (wave reduce)
    float mloc = -3.402823466e38f;
    for (int j = lane; j < deg; j += 64) mloc = fmaxf(mloc, elog[csr[lo + j]]);
#pragma unroll
    for (int o = 32; o >= 1; o >>= 1) mloc = fmaxf(mloc, __shfl_xor(mloc, o));
    float m = mloc;

    // exp weights + weighted gather, 64 edges per chunk
    float acc0 = 0.f, acc1 = 0.f, ssum = 0.f;
    for (int base = 0; base < deg; base += 64) {
        int cnt = min(64, deg - base);
        float w = 0.f; int sidx = 0;
        if (lane < cnt) {
            int eid = csr[lo + base + lane];
            w = __expf(elog[eid] - m);
            sidx = srcv[eid];
        }
        float wl = w;
#pragma unroll
        for (int o = 32; o >= 1; o >>= 1) wl += __shfl_xor(wl, o);
        ssum += wl;
        for (int j = 0; j < cnt; j++) {
            float wj = __shfl(w, j);
            int   sj = __shfl(sidx, j);
            const float* row = XL + (size_t)sj * 128;
            acc0 += wj * row[lane];
            acc1 += wj * row[lane + 64];
        }
    }

    float inv = 1.f / (ssum + 1e-16f);
    float y0 = acc0 * inv + bias[lane];
    float y1 = acc1 * inv + bias[lane + 64];

    // fused LayerNorm over the 128 channels (2 per lane)
    float s = y0 + y1;
#pragma unroll
    for (int o = 32; o >= 1; o >>= 1) s += __shfl_xor(s, o);
    float mean = s * (1.f / 128.f);
    float d0 = y0 - mean, d1 = y1 - mean;
    float v = d0 * d0 + d1 * d1;
#pragma unroll
    for (int o = 32; o >= 1; o >>= 1) v += __shfl_xor(v, o);
    float r = rsqrtf(v * (1.f / 128.f) + 1e-5f);
    float* orow = Xout + (size_t)node * 128;
    orow[lane]      = d0 * r * gamma[lane]      + beta[lane];
    orow[lane + 64] = d1 * r * gamma[lane + 64] + beta[lane + 64];
}

// ---------------------------------------------------------------------------
// Pooling phase 1: batch is sorted, so each block walks a contiguous chunk of
// nodes, run-length accumulates per graph, and emits one atomicAdd per
// (graph-run, channel).  782 blocks -> full occupancy.
// ---------------------------------------------------------------------------
__global__ __launch_bounds__(128) void pool_partial(
    const float* __restrict__ X4, const int* __restrict__ batch,
    float* __restrict__ pooled, int n)
{
    int chunk0 = blockIdx.x * 64;
    if (chunk0 >= n) return;
    int t = threadIdx.x;
    int end = min(chunk0 + 64, n);
    float acc = 0.f;
    int gcur = batch[chunk0];
    for (int r = chunk0; r < end; r++) {
        int g = batch[r];
        if (g != gcur) {
            atomicAdd(&pooled[gcur * 128 + t], acc);
            acc = 0.f; gcur = g;
        }
        acc += X4[(size_t)r * 128 + t];
    }
    atomicAdd(&pooled[gcur * 128 + t], acc);
}

// Pooling phase 2: per-graph mean + final linear + LN + ReLU.
__global__ __launch_bounds__(128) void pool_head(
    const float* __restrict__ pooled, const int* __restrict__ batch,
    const float* __restrict__ Wl, const float* __restrict__ bl,
    const float* __restrict__ gl, const float* __restrict__ bel,
    float* __restrict__ out, int n)
{
    int g = blockIdx.x, t = threadIdx.x;
    int lo = 0, hi = n;
    while (lo < hi) { int mid = (lo + hi) >> 1; if (batch[mid] < g) lo = mid + 1; else hi = mid; }
    int s = lo;
    hi = n;
    while (lo < hi) { int mid = (lo + hi) >> 1; if (batch[mid] < g + 1) lo = mid + 1; else hi = mid; }
    float cntf = (float)(lo - s);

    __shared__ float ps[128];
    __shared__ float red[128];
    ps[t] = pooled[g * 128 + t] / fmaxf(cntf, 1.f);
    __syncthreads();

    float y = bl[t];
    for (int k = 0; k < 128; k++) y += ps[k] * Wl[k * 128 + t];

    red[t] = y; __syncthreads();
#pragma unroll
    for (int o = 64; o >= 1; o >>= 1) { if (t < o) red[t] += red[t + o]; __syncthreads(); }
    float mean = red[0] * (1.f / 128.f); __syncthreads();
    float d = y - mean;
    red[t] = d * d; __syncthreads();
#pragma unroll
    for (int o = 64; o >= 1; o >>= 1) { if (t < o) red[t] += red[t + o]; __syncthreads(); }
    float var = red[0] * (1.f / 128.f);
    float z = d * rsqrtf(var + 1e-5f) * gl[t] + bel[t];
    out[g * 128 + t] = fmaxf(z, 0.f);
}

// ---------------------------------------------------------------------------

extern "C" void kernel_launch(void* const* d_in, const int* in_sizes, int n_in,
                              void* d_out, int out_size, void* d_ws, size_t ws_size,
                              hipStream_t stream)
{
    const float* x    = (const float*)d_in[0];
    const float* ea   = (const float*)d_in[1];
    const float* W1   = (const float*)d_in[2];
    const float* as1  = (const float*)d_in[3];
    const float* ad1  = (const float*)d_in[4];
    const float* We1  = (const float*)d_in[5];
    const float* ae1  = (const float*)d_in[6];
    const float* b1   = (const float*)d_in[7];
    const float* g1   = (const float*)d_in[8];
    const float* be1  = (const float*)d_in[9];
    const float* W2   = (const float*)d_in[10];
    const float* as2  = (const float*)d_in[11];
    const float* ad2  = (const float*)d_in[12];
    const float* We2  = (const float*)d_in[13];
    const float* ae2  = (const float*)d_in[14];
    const float* b2   = (const float*)d_in[15];
    const float* g2   = (const float*)d_in[16];
    const float* be2  = (const float*)d_in[17];
    const float* Wlin = (const float*)d_in[18];
    const float* bl   = (const float*)d_in[19];
    const float* gl   = (const float*)d_in[20];
    const float* bel  = (const float*)d_in[21];
    const int*   ei   = (const int*)d_in[22];
    const int*   batch= (const int*)d_in[23];
    float* out = (float*)d_out;

    int N = in_sizes[0] / 128;
    int E = in_sizes[1] / 32;
    int G = out_size / 128;
    const int* srcv = ei;
    const int* dstv = ei + E;

    char* wsb = (char*)d_ws;
    size_t off = 0;
    auto alloc = [&](size_t bytes) -> void* {
        void* p = wsb + off;
        off += (bytes + 15) & ~(size_t)15;
        return p;
    };
    float* XL     = (float*)alloc((size_t)N * 128 * 4);
    float* XA     = (float*)alloc((size_t)N * 128 * 4);
    float* elog   = (float*)alloc((size_t)E * 4);
    float* edot1  = (float*)alloc((size_t)E * 4);
    float* edot2  = (float*)alloc((size_t)E * 4);
    float* als    = (float*)alloc((size_t)N * 4);
    float* ald    = (float*)alloc((size_t)N * 4);
    float* wa     = (float*)alloc(64 * 4);
    float* pooled = (float*)alloc((size_t)G * 128 * 4);
    int*   counts = (int*)alloc((size_t)N * 4);
    int*   local  = (int*)alloc((size_t)N * 4);
    int*   bsums  = (int*)alloc(256 * 4);
    int*   offs   = (int*)alloc((size_t)(N + 1) * 4);
    int*   cursor = (int*)alloc((size_t)N * 4);
    int*   csr    = (int*)alloc((size_t)E * 4);

    int egrid = (E + 255) / 256;
    int ggrid = (N + 31) / 32;
    int agrid = (N + 3) / 4;
    int pgrid = (N + 63) / 64;
    int sgrid = (N + 1023) / 1024;   // scan blocks (<=256 required; N<=262144 ok)
    int ngrid = (N + 255) / 256;

    // CSR build + edge dots (shared by both layers)
    hipMemsetAsync(counts, 0, (size_t)N * 4, stream);
    hipMemsetAsync(pooled, 0, (size_t)G * 128 * 4, stream);
    prep_wa<<<1, 64, 0, stream>>>(We1, ae1, We2, ae2, wa);
    edge_dots<<<egrid, 256, 0, stream>>>(ea, wa, edot1, edot2, E);
    count_edges<<<egrid, 256, 0, stream>>>(dstv, counts, E);
    scan_local<<<sgrid, 256, 0, stream>>>(counts, local, bsums, N);
    scan_bsums<<<1, 256, 0, stream>>>(bsums, sgrid);
    scan_add<<<ngrid, 256, 0, stream>>>(local, bsums, offs, cursor, N, E);
    scatter_edges<<<egrid, 256, 0, stream>>>(dstv, cursor, csr, E);

    // layer 1
    gemm_node<<<ggrid, 256, 0, stream>>>(x, W1, as1, ad1, XL, als, ald, N);
    edge_logits<<<egrid, 256, 0, stream>>>(edot1, srcv, dstv, als, ald, elog, E);
    aggregate_ln<<<agrid, 256, 0, stream>>>(XL, elog, offs, csr, srcv, b1, g1, be1, XA, N);

    // layer 2
    gemm_node<<<ggrid, 256, 0, stream>>>(XA, W2, as2, ad2, XL, als, ald, N);
    edge_logits<<<egrid, 256, 0, stream>>>(edot2, srcv, dstv, als, ald, elog, E);
    aggregate_ln<<<agrid, 256, 0, stream>>>(XL, elog, offs, csr, srcv, b2, g2, be2, XA, N);

    // pool + head
    pool_partial<<<pgrid, 128, 0, stream>>>(XA, batch, pooled, N);
    pool_head<<<G, 128, 0, stream>>>(pooled, batch, Wlin, bl, gl, bel, out, N);
}

// Round 4
// 488.206 us; speedup vs baseline: 1.6577x; 1.0064x over previous
//
#include <hip/hip_runtime.h>
#include <math.h>

// ---------------------------------------------------------------------------
// Problem shapes: N nodes, D=128 feature dim, ED=32 edge dim, G graphs.
// Accuracy budget: threshold 5.78e-2, fp32 pipeline sits at 3e-5 -> we spend
// some headroom storing the gathered XL matrix as bf16 (halves the dominant
// random-gather traffic in aggregate_ln).  All accumulation stays fp32.
// ---------------------------------------------------------------------------

static __device__ __forceinline__ unsigned short f2bf(float f) {
    unsigned u = __float_as_uint(f);
    unsigned r = (u + 0x7fff + ((u >> 16) & 1)) >> 16;   // round-to-nearest-even
    return (unsigned short)r;
}

// Precompute wa = We @ a_e for both layers (each 32 floats).  ee @ a_e ==
// edge_attr @ (We @ a_e), so the [E,128] edge embedding is never materialized.
__global__ __launch_bounds__(64) void prep_wa(
    const float* __restrict__ We1, const float* __restrict__ ae1,
    const float* __restrict__ We2, const float* __restrict__ ae2,
    float* __restrict__ wa /* 64 floats: wa1[0:32], wa2[32:64] */)
{
    int t = threadIdx.x;
    const float* We = (t < 32) ? We1 : We2;
    const float* ae = (t < 32) ? ae1 : ae2;
    int r = t & 31;
    float s = 0.f;
    for (int c = 0; c < 128; c++) s += We[r*128 + c] * ae[c];
    wa[t] = s;
}

// One pass over edge_attr (77 MB) computing BOTH layers' edge dots.
__global__ __launch_bounds__(256) void edge_dots(
    const float* __restrict__ ea, const float* __restrict__ wa,
    float* __restrict__ edot1, float* __restrict__ edot2, int E)
{
    int j = blockIdx.x * 256 + threadIdx.x;
    if (j >= E) return;
    const float4* e4 = (const float4*)(ea + (size_t)j * 32);
    float s1 = 0.f, s2 = 0.f;
#pragma unroll
    for (int i = 0; i < 8; i++) {
        float4 v = e4[i];
        float4 w1 = ((const float4*)wa)[i];
        float4 w2 = ((const float4*)(wa + 32))[i];
        s1 += v.x*w1.x + v.y*w1.y + v.z*w1.z + v.w*w1.w;
        s2 += v.x*w2.x + v.y*w2.y + v.z*w2.z + v.w*w2.w;
    }
    edot1[j] = s1; edot2[j] = s2;
}

// ---------------------------------------------------------------------------
// Node GEMM: XLb = bf16(X @ W)  (N x 128 @ 128 x 128), fused per-row dots
// with a_src / a_dst.  32 rows per 256-thread block, 4x4 outputs per thread.
// fp32 XL is never materialized: only the aggregate gather consumes it.
// ---------------------------------------------------------------------------
__global__ __launch_bounds__(256) void gemm_node(
    const float* __restrict__ X, const float* __restrict__ W,
    const float* __restrict__ asrc, const float* __restrict__ adst,
    unsigned short* __restrict__ XLb, float* __restrict__ als, float* __restrict__ ald,
    int nrows)
{
    __shared__ float Wl[64 * 128];     // 32 KB (half of W at a time)
    __shared__ float Xs[32 * 132];     // 16.5 KB, padded stride 132
    int t = threadIdx.x;
    int row0 = blockIdx.x * 32;
    int nr = min(32, nrows - row0);

    for (int i = t; i < nr * 32; i += 256) {
        int r = i >> 5, cc = i & 31;
        float4 v = ((const float4*)(X + (size_t)(row0 + r) * 128))[cc];
        *(float4*)(Xs + r * 132 + cc * 4) = v;
    }

    int tr = t >> 5;
    int tc = t & 31;
    float acc[4][4];
#pragma unroll
    for (int i = 0; i < 4; i++)
#pragma unroll
        for (int j = 0; j < 4; j++) acc[i][j] = 0.f;

    const float4* W4 = (const float4*)W;
    float4* Wl4 = (float4*)Wl;

    for (int kt = 0; kt < 128; kt += 64) {
        __syncthreads();
#pragma unroll
        for (int i = 0; i < 8; i++)
            Wl4[t + 256 * i] = W4[kt * 32 + t + 256 * i];
        __syncthreads();

        for (int k = 0; k < 64; k += 4) {
            float xk[4][4];
#pragma unroll
            for (int i = 0; i < 4; i++) {
                float4 v = *(const float4*)(Xs + (tr * 4 + i) * 132 + kt + k);
                xk[i][0] = v.x; xk[i][1] = v.y; xk[i][2] = v.z; xk[i][3] = v.w;
            }
#pragma unroll
            for (int kk = 0; kk < 4; kk++) {
                float4 w = *(const float4*)(Wl + (k + kk) * 128 + tc * 4);
#pragma unroll
                for (int i = 0; i < 4; i++) {
                    float xs = xk[i][kk];
                    acc[i][0] += xs * w.x; acc[i][1] += xs * w.y;
                    acc[i][2] += xs * w.z; acc[i][3] += xs * w.w;
                }
            }
        }
    }

#pragma unroll
    for (int i = 0; i < 4; i++) {
        int r = tr * 4 + i;
        if (r < nr) {
            ushort4 v;
            v.x = f2bf(acc[i][0]); v.y = f2bf(acc[i][1]);
            v.z = f2bf(acc[i][2]); v.w = f2bf(acc[i][3]);
            *(ushort4*)(XLb + (size_t)(row0 + r) * 128 + tc * 4) = v;
        }
    }

    float a_s[4], a_d[4];
#pragma unroll
    for (int j = 0; j < 4; j++) { a_s[j] = asrc[tc*4 + j]; a_d[j] = adst[tc*4 + j]; }
#pragma unroll
    for (int i = 0; i < 4; i++) {
        float ps = acc[i][0]*a_s[0] + acc[i][1]*a_s[1] + acc[i][2]*a_s[2] + acc[i][3]*a_s[3];
        float pd = acc[i][0]*a_d[0] + acc[i][1]*a_d[1] + acc[i][2]*a_d[2] + acc[i][3]*a_d[3];
#pragma unroll
        for (int o = 16; o >= 1; o >>= 1) {
            ps += __shfl_down(ps, o, 32);
            pd += __shfl_down(pd, o, 32);
        }
        if (tc == 0) {
            int r = tr * 4 + i;
            if (r < nr) { als[row0 + r] = ps; ald[row0 + r] = pd; }
        }
    }
}

// ---------------------------------------------------------------------------
// Per-edge logits from precomputed edge dot: e = lrelu(als[src]+ald[dst]+edot)
// ---------------------------------------------------------------------------
__global__ __launch_bounds__(256) void edge_logits(
    const float* __restrict__ edot, const int* __restrict__ srcv, const int* __restrict__ dstv,
    const float* __restrict__ als, const float* __restrict__ ald,
    float* __restrict__ elog, int E)
{
    int j = blockIdx.x * 256 + threadIdx.x;
    if (j >= E) return;
    float s = edot[j] + als[srcv[j]] + ald[dstv[j]];
    elog[j] = (s >= 0.f) ? s : 0.2f * s;
}

// ---------------------------------------------------------------------------
// CSR-by-dst construction (edge_index identical across both layers)
// ---------------------------------------------------------------------------
__global__ __launch_bounds__(256) void count_edges(
    const int* __restrict__ dstv, int* __restrict__ counts, int E)
{
    int j = blockIdx.x * 256 + threadIdx.x;
    if (j < E) atomicAdd(&counts[dstv[j]], 1);
}

// Hierarchical exclusive scan: 1024 counts per block.
__global__ __launch_bounds__(256) void scan_local(
    const int* __restrict__ counts, int* __restrict__ local,
    int* __restrict__ bsums, int n)
{
    __shared__ int tmp[256];
    int b = blockIdx.x, t = threadIdx.x;
    int base = b * 1024 + t * 4;
    int v0 = 0, v1 = 0, v2 = 0, v3 = 0;
    if (base + 3 < n) {
        const int4 c4 = *(const int4*)(counts + base);
        v0 = c4.x; v1 = c4.y; v2 = c4.z; v3 = c4.w;
    } else {
        if (base + 0 < n) v0 = counts[base + 0];
        if (base + 1 < n) v1 = counts[base + 1];
        if (base + 2 < n) v2 = counts[base + 2];
        if (base + 3 < n) v3 = counts[base + 3];
    }
    tmp[t] = v0 + v1 + v2 + v3; __syncthreads();
    for (int o = 1; o < 256; o <<= 1) {
        int x = (t >= o) ? tmp[t - o] : 0;
        __syncthreads();
        tmp[t] += x;
        __syncthreads();
    }
    int run = (t == 0) ? 0 : tmp[t - 1];
    if (base + 0 < n) { local[base + 0] = run; run += v0; }
    if (base + 1 < n) { local[base + 1] = run; run += v1; }
    if (base + 2 < n) { local[base + 2] = run; run += v2; }
    if (base + 3 < n) { local[base + 3] = run; }
    if (t == 255) bsums[b] = tmp[255];
}

__global__ __launch_bounds__(256) void scan_bsums(int* __restrict__ bsums, int nb)
{
    __shared__ int tmp[256];
    int t = threadIdx.x;
    tmp[t] = (t < nb) ? bsums[t] : 0; __syncthreads();
    for (int o = 1; o < 256; o <<= 1) {
        int x = (t >= o) ? tmp[t - o] : 0;
        __syncthreads();
        tmp[t] += x;
        __syncthreads();
    }
    if (t < nb) bsums[t] = (t == 0) ? 0 : tmp[t - 1];
}

__global__ __launch_bounds__(256) void scan_add(
    const int* __restrict__ local, const int* __restrict__ bsums,
    int* __restrict__ offs, int* __restrict__ cursor, int n, int E)
{
    int i = blockIdx.x * 256 + threadIdx.x;
    if (i < n) {
        int v = local[i] + bsums[i >> 10];
        offs[i] = v; cursor[i] = v;
    }
    if (i == 0) offs[n] = E;
}

__global__ __launch_bounds__(256) void scatter_edges(
    const int* __restrict__ dstv, int* __restrict__ cursor, int* __restrict__ csr, int E)
{
    int j = blockIdx.x * 256 + threadIdx.x;
    if (j < E) { int p = atomicAdd(&cursor[dstv[j]], 1); csr[p] = j; }
}

// ---------------------------------------------------------------------------
// Wave-synchronous per-dst-node segment softmax + weighted bf16 gather + bias
// + LN.  One node per 64-lane wave (4 / block).  Each lane owns channels
// {2*lane, 2*lane+1}: ONE dword load per edge per lane (2 packed bf16),
// unpacked with two shifts — no cvt, half the bytes of the fp32 version.
// ---------------------------------------------------------------------------
__global__ __launch_bounds__(256) void aggregate_ln(
    const unsigned short* __restrict__ XLb, const float* __restrict__ elog,
    const int* __restrict__ offs, const int* __restrict__ csr, const int* __restrict__ srcv,
    const float* __restrict__ bias, const float* __restrict__ gamma, const float* __restrict__ beta,
    float* __restrict__ Xout, int N)
{
    int node = blockIdx.x * 4 + (threadIdx.x >> 6);
    if (node >= N) return;
    int lane = threadIdx.x & 63;
    int lo = offs[node], hi = offs[node + 1];
    int deg = hi - lo;

    // segment max (wave reduce)
    float mloc = -3.402823466e38f;
    for (int j = lane; j < deg; j += 64) mloc = fmaxf(mloc, elog[csr[lo + j]]);
#pragma unroll
    for (int o = 32; o >= 1; o >>= 1) mloc = fmaxf(mloc, __shfl_xor(mloc, o));
    float m = mloc;

    // exp weights + weighted gather, 64 edges per chunk
    float acc0 = 0.f, acc1 = 0.f, ssum = 0.f;
    for (int base = 0; base < deg; base += 64) {
        int cnt = min(64, deg - base);
        float w = 0.f; int sidx = 0;
        if (lane < cnt) {
            int eid = csr[lo + base + lane];
            w = __expf(elog[eid] - m);
            sidx = srcv[eid];
        }
        float wl = w;
#pragma unroll
        for (int o = 32; o >= 1; o >>= 1) wl += __shfl_xor(wl, o);
        ssum += wl;
        for (int j = 0; j < cnt; j++) {
            float wj = __shfl(w, j);
            int   sj = __shfl(sidx, j);
            unsigned u = *(const unsigned*)(XLb + ((size_t)sj << 7) + (lane << 1));
            acc0 += wj * __uint_as_float(u << 16);
            acc1 += wj * __uint_as_float(u & 0xffff0000u);
        }
    }

    float2 bi = *(const float2*)(bias  + 2 * lane);
    float inv = 1.f / (ssum + 1e-16f);
    float y0 = acc0 * inv + bi.x;
    float y1 = acc1 * inv + bi.y;

    // fused LayerNorm over the 128 channels (2 per lane)
    float s = y0 + y1;
#pragma unroll
    for (int o = 32; o >= 1; o >>= 1) s += __shfl_xor(s, o);
    float mean = s * (1.f / 128.f);
    float d0 = y0 - mean, d1 = y1 - mean;
    float v = d0 * d0 + d1 * d1;
#pragma unroll
    for (int o = 32; o >= 1; o >>= 1) v += __shfl_xor(v, o);
    float r = rsqrtf(v * (1.f / 128.f) + 1e-5f);
    float2 ga = *(const float2*)(gamma + 2 * lane);
    float2 be = *(const float2*)(beta  + 2 * lane);
    float2 o2;
    o2.x = d0 * r * ga.x + be.x;
    o2.y = d1 * r * ga.y + be.y;
    *(float2*)(Xout + (size_t)node * 128 + 2 * lane) = o2;
}

// ---------------------------------------------------------------------------
// Pooling phase 1: batch sorted; run-length accumulate, one atomicAdd per
// (graph-run, channel).
// ---------------------------------------------------------------------------
__global__ __launch_bounds__(128) void pool_partial(
    const float* __restrict__ X4, const int* __restrict__ batch,
    float* __restrict__ pooled, int n)
{
    int chunk0 = blockIdx.x * 64;
    if (chunk0 >= n) return;
    int t = threadIdx.x;
    int end = min(chunk0 + 64, n);
    float acc = 0.f;
    int gcur = batch[chunk0];
    for (int r = chunk0; r < end; r++) {
        int g = batch[r];
        if (g != gcur) {
            atomicAdd(&pooled[gcur * 128 + t], acc);
            acc = 0.f; gcur = g;
        }
        acc += X4[(size_t)r * 128 + t];
    }
    atomicAdd(&pooled[gcur * 128 + t], acc);
}

// Pooling phase 2: per-graph mean + final linear + LN + ReLU.
__global__ __launch_bounds__(128) void pool_head(
    const float* __restrict__ pooled, const int* __restrict__ batch,
    const float* __restrict__ Wl, const float* __restrict__ bl,
    const float* __restrict__ gl, const float* __restrict__ bel,
    float* __restrict__ out, int n)
{
    int g = blockIdx.x, t = threadIdx.x;
    int lo = 0, hi = n;
    while (lo < hi) { int mid = (lo + hi) >> 1; if (batch[mid] < g) lo = mid + 1; else hi = mid; }
    int s = lo;
    hi = n;
    while (lo < hi) { int mid = (lo + hi) >> 1; if (batch[mid] < g + 1) lo = mid + 1; else hi = mid; }
    float cntf = (float)(lo - s);

    __shared__ float ps[128];
    __shared__ float red[128];
    ps[t] = pooled[g * 128 + t] / fmaxf(cntf, 1.f);
    __syncthreads();

    float y = bl[t];
    for (int k = 0; k < 128; k++) y += ps[k] * Wl[k * 128 + t];

    red[t] = y; __syncthreads();
#pragma unroll
    for (int o = 64; o >= 1; o >>= 1) { if (t < o) red[t] += red[t + o]; __syncthreads(); }
    float mean = red[0] * (1.f / 128.f); __syncthreads();
    float d = y - mean;
    red[t] = d * d; __syncthreads();
#pragma unroll
    for (int o = 64; o >= 1; o >>= 1) { if (t < o) red[t] += red[t + o]; __syncthreads(); }
    float var = red[0] * (1.f / 128.f);
    float z = d * rsqrtf(var + 1e-5f) * gl[t] + bel[t];
    out[g * 128 + t] = fmaxf(z, 0.f);
}

// ---------------------------------------------------------------------------

extern "C" void kernel_launch(void* const* d_in, const int* in_sizes, int n_in,
                              void* d_out, int out_size, void* d_ws, size_t ws_size,
                              hipStream_t stream)
{
    const float* x    = (const float*)d_in[0];
    const float* ea   = (const float*)d_in[1];
    const float* W1   = (const float*)d_in[2];
    const float* as1  = (const float*)d_in[3];
    const float* ad1  = (const float*)d_in[4];
    const float* We1  = (const float*)d_in[5];
    const float* ae1  = (const float*)d_in[6];
    const float* b1   = (const float*)d_in[7];
    const float* g1   = (const float*)d_in[8];
    const float* be1  = (const float*)d_in[9];
    const float* W2   = (const float*)d_in[10];
    const float* as2  = (const float*)d_in[11];
    const float* ad2  = (const float*)d_in[12];
    const float* We2  = (const float*)d_in[13];
    const float* ae2  = (const float*)d_in[14];
    const float* b2   = (const float*)d_in[15];
    const float* g2   = (const float*)d_in[16];
    const float* be2  = (const float*)d_in[17];
    const float* Wlin = (const float*)d_in[18];
    const float* bl   = (const float*)d_in[19];
    const float* gl   = (const float*)d_in[20];
    const float* bel  = (const float*)d_in[21];
    const int*   ei   = (const int*)d_in[22];
    const int*   batch= (const int*)d_in[23];
    float* out = (float*)d_out;

    int N = in_sizes[0] / 128;
    int E = in_sizes[1] / 32;
    int G = out_size / 128;
    const int* srcv = ei;
    const int* dstv = ei + E;

    char* wsb = (char*)d_ws;
    size_t off = 0;
    auto alloc = [&](size_t bytes) -> void* {
        void* p = wsb + off;
        off += (bytes + 15) & ~(size_t)15;
        return p;
    };
    unsigned short* XLb = (unsigned short*)alloc((size_t)N * 128 * 2);
    float* XA     = (float*)alloc((size_t)N * 128 * 4);
    float* elog   = (float*)alloc((size_t)E * 4);
    float* edot1  = (float*)alloc((size_t)E * 4);
    float* edot2  = (float*)alloc((size_t)E * 4);
    float* als    = (float*)alloc((size_t)N * 4);
    float* ald    = (float*)alloc((size_t)N * 4);
    float* wa     = (float*)alloc(64 * 4);
    float* pooled = (float*)alloc((size_t)G * 128 * 4);
    int*   counts = (int*)alloc((size_t)N * 4);
    int*   local  = (int*)alloc((size_t)N * 4);
    int*   bsums  = (int*)alloc(256 * 4);
    int*   offs   = (int*)alloc((size_t)(N + 1) * 4);
    int*   cursor = (int*)alloc((size_t)N * 4);
    int*   csr    = (int*)alloc((size_t)E * 4);

    int egrid = (E + 255) / 256;
    int ggrid = (N + 31) / 32;
    int agrid = (N + 3) / 4;
    int pgrid = (N + 63) / 64;
    int sgrid = (N + 1023) / 1024;   // scan blocks (<=256 required; N<=262144 ok)
    int ngrid = (N + 255) / 256;

    // CSR build + edge dots (shared by both layers)
    hipMemsetAsync(counts, 0, (size_t)N * 4, stream);
    hipMemsetAsync(pooled, 0, (size_t)G * 128 * 4, stream);
    prep_wa<<<1, 64, 0, stream>>>(We1, ae1, We2, ae2, wa);
    edge_dots<<<egrid, 256, 0, stream>>>(ea, wa, edot1, edot2, E);
    count_edges<<<egrid, 256, 0, stream>>>(dstv, counts, E);
    scan_local<<<sgrid, 256, 0, stream>>>(counts, local, bsums, N);
    scan_bsums<<<1, 256, 0, stream>>>(bsums, sgrid);
    scan_add<<<ngrid, 256, 0, stream>>>(local, bsums, offs, cursor, N, E);
    scatter_edges<<<egrid, 256, 0, stream>>>(dstv, cursor, csr, E);

    // layer 1
    gemm_node<<<ggrid, 256, 0, stream>>>(x, W1, as1, ad1, XLb, als, ald, N);
    edge_logits<<<egrid, 256, 0, stream>>>(edot1, srcv, dstv, als, ald, elog, E);
    aggregate_ln<<<agrid, 256, 0, stream>>>(XLb, elog, offs, csr, srcv, b1, g1, be1, XA, N);

    // layer 2
    gemm_node<<<ggrid, 256, 0, stream>>>(XA, W2, as2, ad2, XLb, als, ald, N);
    edge_logits<<<egrid, 256, 0, stream>>>(edot2, srcv, dstv, als, ald, elog, E);
    aggregate_ln<<<agrid, 256, 0, stream>>>(XLb, elog, offs, csr, srcv, b2, g2, be2, XA, N);

    // pool + head
    pool_partial<<<pgrid, 128, 0, stream>>>(XA, batch, pooled, N);
    pool_head<<<G, 128, 0, stream>>>(pooled, batch, Wlin, bl, gl, bel, out, N);
}

// Round 5
// 451.813 us; speedup vs baseline: 1.7913x; 1.0805x over previous
//
#include <hip/hip_runtime.h>
#include <math.h>

// ---------------------------------------------------------------------------
// Problem shapes: N nodes, D=128 feature dim, ED=32 edge dim, G graphs.
// Accuracy budget: threshold 5.78e-2; bf16 XL gather keeps us at ~1.6e-2.
// aggregate_ln design: CSR-ordered payloads (srcc/elogc) so the only random
// stream is the bf16 row gather, unrolled x4 for memory-level parallelism;
// all softmax bookkeeping is wave-uniform (no shuffles, no reductions).
// ---------------------------------------------------------------------------

static __device__ __forceinline__ unsigned short f2bf(float f) {
    unsigned u = __float_as_uint(f);
    unsigned r = (u + 0x7fff + ((u >> 16) & 1)) >> 16;   // round-to-nearest-even
    return (unsigned short)r;
}

// Precompute wa = We @ a_e for both layers (each 32 floats).
__global__ __launch_bounds__(64) void prep_wa(
    const float* __restrict__ We1, const float* __restrict__ ae1,
    const float* __restrict__ We2, const float* __restrict__ ae2,
    float* __restrict__ wa /* 64 floats: wa1[0:32], wa2[32:64] */)
{
    int t = threadIdx.x;
    const float* We = (t < 32) ? We1 : We2;
    const float* ae = (t < 32) ? ae1 : ae2;
    int r = t & 31;
    float s = 0.f;
    for (int c = 0; c < 128; c++) s += We[r*128 + c] * ae[c];
    wa[t] = s;
}

// One pass over edge_attr (77 MB) computing BOTH layers' edge dots.
__global__ __launch_bounds__(256) void edge_dots(
    const float* __restrict__ ea, const float* __restrict__ wa,
    float* __restrict__ edot1, float* __restrict__ edot2, int E)
{
    int j = blockIdx.x * 256 + threadIdx.x;
    if (j >= E) return;
    const float4* e4 = (const float4*)(ea + (size_t)j * 32);
    float s1 = 0.f, s2 = 0.f;
#pragma unroll
    for (int i = 0; i < 8; i++) {
        float4 v = e4[i];
        float4 w1 = ((const float4*)wa)[i];
        float4 w2 = ((const float4*)(wa + 32))[i];
        s1 += v.x*w1.x + v.y*w1.y + v.z*w1.z + v.w*w1.w;
        s2 += v.x*w2.x + v.y*w2.y + v.z*w2.z + v.w*w2.w;
    }
    edot1[j] = s1; edot2[j] = s2;
}

// ---------------------------------------------------------------------------
// Node GEMM: XLb = bf16(X @ W), fused per-row dots with a_src / a_dst.
// ---------------------------------------------------------------------------
__global__ __launch_bounds__(256) void gemm_node(
    const float* __restrict__ X, const float* __restrict__ W,
    const float* __restrict__ asrc, const float* __restrict__ adst,
    unsigned short* __restrict__ XLb, float* __restrict__ als, float* __restrict__ ald,
    int nrows)
{
    __shared__ float Wl[64 * 128];     // 32 KB (half of W at a time)
    __shared__ float Xs[32 * 132];     // 16.5 KB, padded stride 132
    int t = threadIdx.x;
    int row0 = blockIdx.x * 32;
    int nr = min(32, nrows - row0);

    for (int i = t; i < nr * 32; i += 256) {
        int r = i >> 5, cc = i & 31;
        float4 v = ((const float4*)(X + (size_t)(row0 + r) * 128))[cc];
        *(float4*)(Xs + r * 132 + cc * 4) = v;
    }

    int tr = t >> 5;
    int tc = t & 31;
    float acc[4][4];
#pragma unroll
    for (int i = 0; i < 4; i++)
#pragma unroll
        for (int j = 0; j < 4; j++) acc[i][j] = 0.f;

    const float4* W4 = (const float4*)W;
    float4* Wl4 = (float4*)Wl;

    for (int kt = 0; kt < 128; kt += 64) {
        __syncthreads();
#pragma unroll
        for (int i = 0; i < 8; i++)
            Wl4[t + 256 * i] = W4[kt * 32 + t + 256 * i];
        __syncthreads();

        for (int k = 0; k < 64; k += 4) {
            float xk[4][4];
#pragma unroll
            for (int i = 0; i < 4; i++) {
                float4 v = *(const float4*)(Xs + (tr * 4 + i) * 132 + kt + k);
                xk[i][0] = v.x; xk[i][1] = v.y; xk[i][2] = v.z; xk[i][3] = v.w;
            }
#pragma unroll
            for (int kk = 0; kk < 4; kk++) {
                float4 w = *(const float4*)(Wl + (k + kk) * 128 + tc * 4);
#pragma unroll
                for (int i = 0; i < 4; i++) {
                    float xs = xk[i][kk];
                    acc[i][0] += xs * w.x; acc[i][1] += xs * w.y;
                    acc[i][2] += xs * w.z; acc[i][3] += xs * w.w;
                }
            }
        }
    }

#pragma unroll
    for (int i = 0; i < 4; i++) {
        int r = tr * 4 + i;
        if (r < nr) {
            ushort4 v;
            v.x = f2bf(acc[i][0]); v.y = f2bf(acc[i][1]);
            v.z = f2bf(acc[i][2]); v.w = f2bf(acc[i][3]);
            *(ushort4*)(XLb + (size_t)(row0 + r) * 128 + tc * 4) = v;
        }
    }

    float a_s[4], a_d[4];
#pragma unroll
    for (int j = 0; j < 4; j++) { a_s[j] = asrc[tc*4 + j]; a_d[j] = adst[tc*4 + j]; }
#pragma unroll
    for (int i = 0; i < 4; i++) {
        float ps = acc[i][0]*a_s[0] + acc[i][1]*a_s[1] + acc[i][2]*a_s[2] + acc[i][3]*a_s[3];
        float pd = acc[i][0]*a_d[0] + acc[i][1]*a_d[1] + acc[i][2]*a_d[2] + acc[i][3]*a_d[3];
#pragma unroll
        for (int o = 16; o >= 1; o >>= 1) {
            ps += __shfl_down(ps, o, 32);
            pd += __shfl_down(pd, o, 32);
        }
        if (tc == 0) {
            int r = tr * 4 + i;
            if (r < nr) { als[row0 + r] = ps; ald[row0 + r] = pd; }
        }
    }
}

// ---------------------------------------------------------------------------
// Per-edge logits, written directly in CSR order via rank[]:
// elogc[rank[j]] = lrelu(als[src]+ald[dst]+edot[j])
// ---------------------------------------------------------------------------
__global__ __launch_bounds__(256) void edge_logits(
    const float* __restrict__ edot, const int* __restrict__ srcv, const int* __restrict__ dstv,
    const int* __restrict__ rank,
    const float* __restrict__ als, const float* __restrict__ ald,
    float* __restrict__ elogc, int E)
{
    int j = blockIdx.x * 256 + threadIdx.x;
    if (j >= E) return;
    float s = edot[j] + als[srcv[j]] + ald[dstv[j]];
    elogc[rank[j]] = (s >= 0.f) ? s : 0.2f * s;
}

// ---------------------------------------------------------------------------
// CSR-by-dst construction (edge_index identical across both layers)
// ---------------------------------------------------------------------------
__global__ __launch_bounds__(256) void count_edges(
    const int* __restrict__ dstv, int* __restrict__ counts, int E)
{
    int j = blockIdx.x * 256 + threadIdx.x;
    if (j < E) atomicAdd(&counts[dstv[j]], 1);
}

// Hierarchical exclusive scan: 1024 counts per block.
__global__ __launch_bounds__(256) void scan_local(
    const int* __restrict__ counts, int* __restrict__ local,
    int* __restrict__ bsums, int n)
{
    __shared__ int tmp[256];
    int b = blockIdx.x, t = threadIdx.x;
    int base = b * 1024 + t * 4;
    int v0 = 0, v1 = 0, v2 = 0, v3 = 0;
    if (base + 3 < n) {
        const int4 c4 = *(const int4*)(counts + base);
        v0 = c4.x; v1 = c4.y; v2 = c4.z; v3 = c4.w;
    } else {
        if (base + 0 < n) v0 = counts[base + 0];
        if (base + 1 < n) v1 = counts[base + 1];
        if (base + 2 < n) v2 = counts[base + 2];
        if (base + 3 < n) v3 = counts[base + 3];
    }
    tmp[t] = v0 + v1 + v2 + v3; __syncthreads();
    for (int o = 1; o < 256; o <<= 1) {
        int x = (t >= o) ? tmp[t - o] : 0;
        __syncthreads();
        tmp[t] += x;
        __syncthreads();
    }
    int run = (t == 0) ? 0 : tmp[t - 1];
    if (base + 0 < n) { local[base + 0] = run; run += v0; }
    if (base + 1 < n) { local[base + 1] = run; run += v1; }
    if (base + 2 < n) { local[base + 2] = run; run += v2; }
    if (base + 3 < n) { local[base + 3] = run; }
    if (t == 255) bsums[b] = tmp[255];
}

__global__ __launch_bounds__(256) void scan_bsums(int* __restrict__ bsums, int nb)
{
    __shared__ int tmp[256];
    int t = threadIdx.x;
    tmp[t] = (t < nb) ? bsums[t] : 0; __syncthreads();
    for (int o = 1; o < 256; o <<= 1) {
        int x = (t >= o) ? tmp[t - o] : 0;
        __syncthreads();
        tmp[t] += x;
        __syncthreads();
    }
    if (t < nb) bsums[t] = (t == 0) ? 0 : tmp[t - 1];
}

__global__ __launch_bounds__(256) void scan_add(
    const int* __restrict__ local, const int* __restrict__ bsums,
    int* __restrict__ offs, int* __restrict__ cursor, int n, int E)
{
    int i = blockIdx.x * 256 + threadIdx.x;
    if (i < n) {
        int v = local[i] + bsums[i >> 10];
        offs[i] = v; cursor[i] = v;
    }
    if (i == 0) offs[n] = E;
}

// scatter: permute src into CSR order, remember each edge's CSR slot (rank).
__global__ __launch_bounds__(256) void scatter_edges(
    const int* __restrict__ srcv, const int* __restrict__ dstv,
    int* __restrict__ cursor, int* __restrict__ srcc, int* __restrict__ rank, int E)
{
    int j = blockIdx.x * 256 + threadIdx.x;
    if (j < E) {
        int p = atomicAdd(&cursor[dstv[j]], 1);
        srcc[p] = srcv[j];
        rank[j] = p;
    }
}

// ---------------------------------------------------------------------------
// Per-dst-node segment softmax + weighted bf16 row gather + bias + LN.
// One node per 64-lane wave (4/block).  srcc/elogc are CSR-contiguous, so
// all softmax bookkeeping is wave-uniform: no shuffles for weights, no ssum
// reduction.  Row gather unrolled x4 -> 4 independent loads in flight.
// ---------------------------------------------------------------------------
__global__ __launch_bounds__(256) void aggregate_ln(
    const unsigned short* __restrict__ XLb, const float* __restrict__ elogc,
    const int* __restrict__ offs, const int* __restrict__ srcc,
    const float* __restrict__ bias, const float* __restrict__ gamma, const float* __restrict__ beta,
    float* __restrict__ Xout, int N)
{
    int node = blockIdx.x * 4 + (threadIdx.x >> 6);
    if (node >= N) return;
    int lane = threadIdx.x & 63;
    int lo = offs[node], hi = offs[node + 1];
    int deg = hi - lo;

    // segment max over contiguous elogc[lo:hi)
    float mloc = -3.402823466e38f;
    for (int j = lane; j < deg; j += 64) mloc = fmaxf(mloc, elogc[lo + j]);
#pragma unroll
    for (int o = 32; o >= 1; o >>= 1) mloc = fmaxf(mloc, __shfl_xor(mloc, o));
    float m = mloc;

    const unsigned* rows = (const unsigned*)XLb;   // row s: rows + s*64; lane owns dword `lane`
    float acc0 = 0.f, acc1 = 0.f, ssum = 0.f;      // ssum identical across lanes
    int j = 0;
    for (; j + 4 <= deg; j += 4) {
        int   s0 = srcc[lo + j],     s1 = srcc[lo + j + 1];
        int   s2 = srcc[lo + j + 2], s3 = srcc[lo + j + 3];
        float e0 = elogc[lo + j],     e1 = elogc[lo + j + 1];
        float e2 = elogc[lo + j + 2], e3 = elogc[lo + j + 3];
        unsigned u0 = rows[((size_t)s0 << 6) + lane];
        unsigned u1 = rows[((size_t)s1 << 6) + lane];
        unsigned u2 = rows[((size_t)s2 << 6) + lane];
        unsigned u3 = rows[((size_t)s3 << 6) + lane];
        float w0 = __expf(e0 - m), w1 = __expf(e1 - m);
        float w2 = __expf(e2 - m), w3 = __expf(e3 - m);
        ssum += (w0 + w1) + (w2 + w3);
        acc0 += w0 * __uint_as_float(u0 << 16);
        acc1 += w0 * __uint_as_float(u0 & 0xffff0000u);
        acc0 += w1 * __uint_as_float(u1 << 16);
        acc1 += w1 * __uint_as_float(u1 & 0xffff0000u);
        acc0 += w2 * __uint_as_float(u2 << 16);
        acc1 += w2 * __uint_as_float(u2 & 0xffff0000u);
        acc0 += w3 * __uint_as_float(u3 << 16);
        acc1 += w3 * __uint_as_float(u3 & 0xffff0000u);
    }
    for (; j < deg; j++) {
        int   s0 = srcc[lo + j];
        float w0 = __expf(elogc[lo + j] - m);
        unsigned u0 = rows[((size_t)s0 << 6) + lane];
        ssum += w0;
        acc0 += w0 * __uint_as_float(u0 << 16);
        acc1 += w0 * __uint_as_float(u0 & 0xffff0000u);
    }

    float2 bi = *(const float2*)(bias + 2 * lane);
    float inv = 1.f / (ssum + 1e-16f);
    float y0 = acc0 * inv + bi.x;
    float y1 = acc1 * inv + bi.y;

    // fused LayerNorm over the 128 channels (2 per lane)
    float s = y0 + y1;
#pragma unroll
    for (int o = 32; o >= 1; o >>= 1) s += __shfl_xor(s, o);
    float mean = s * (1.f / 128.f);
    float d0 = y0 - mean, d1 = y1 - mean;
    float v = d0 * d0 + d1 * d1;
#pragma unroll
    for (int o = 32; o >= 1; o >>= 1) v += __shfl_xor(v, o);
    float r = rsqrtf(v * (1.f / 128.f) + 1e-5f);
    float2 ga = *(const float2*)(gamma + 2 * lane);
    float2 be = *(const float2*)(beta  + 2 * lane);
    float2 o2;
    o2.x = d0 * r * ga.x + be.x;
    o2.y = d1 * r * ga.y + be.y;
    *(float2*)(Xout + (size_t)node * 128 + 2 * lane) = o2;
}

// ---------------------------------------------------------------------------
// Pooling phase 1: batch sorted; run-length accumulate, one atomicAdd per
// (graph-run, channel).
// ---------------------------------------------------------------------------
__global__ __launch_bounds__(128) void pool_partial(
    const float* __restrict__ X4, const int* __restrict__ batch,
    float* __restrict__ pooled, int n)
{
    int chunk0 = blockIdx.x * 64;
    if (chunk0 >= n) return;
    int t = threadIdx.x;
    int end = min(chunk0 + 64, n);
    float acc = 0.f;
    int gcur = batch[chunk0];
    for (int r = chunk0; r < end; r++) {
        int g = batch[r];
        if (g != gcur) {
            atomicAdd(&pooled[gcur * 128 + t], acc);
            acc = 0.f; gcur = g;
        }
        acc += X4[(size_t)r * 128 + t];
    }
    atomicAdd(&pooled[gcur * 128 + t], acc);
}

// Pooling phase 2: per-graph mean + final linear + LN + ReLU.
__global__ __launch_bounds__(128) void pool_head(
    const float* __restrict__ pooled, const int* __restrict__ batch,
    const float* __restrict__ Wl, const float* __restrict__ bl,
    const float* __restrict__ gl, const float* __restrict__ bel,
    float* __restrict__ out, int n)
{
    int g = blockIdx.x, t = threadIdx.x;
    int lo = 0, hi = n;
    while (lo < hi) { int mid = (lo + hi) >> 1; if (batch[mid] < g) lo = mid + 1; else hi = mid; }
    int s = lo;
    hi = n;
    while (lo < hi) { int mid = (lo + hi) >> 1; if (batch[mid] < g + 1) lo = mid + 1; else hi = mid; }
    float cntf = (float)(lo - s);

    __shared__ float ps[128];
    __shared__ float red[128];
    ps[t] = pooled[g * 128 + t] / fmaxf(cntf, 1.f);
    __syncthreads();

    float y = bl[t];
    for (int k = 0; k < 128; k++) y += ps[k] * Wl[k * 128 + t];

    red[t] = y; __syncthreads();
#pragma unroll
    for (int o = 64; o >= 1; o >>= 1) { if (t < o) red[t] += red[t + o]; __syncthreads(); }
    float mean = red[0] * (1.f / 128.f); __syncthreads();
    float d = y - mean;
    red[t] = d * d; __syncthreads();
#pragma unroll
    for (int o = 64; o >= 1; o >>= 1) { if (t < o) red[t] += red[t + o]; __syncthreads(); }
    float var = red[0] * (1.f / 128.f);
    float z = d * rsqrtf(var + 1e-5f) * gl[t] + bel[t];
    out[g * 128 + t] = fmaxf(z, 0.f);
}

// ---------------------------------------------------------------------------

extern "C" void kernel_launch(void* const* d_in, const int* in_sizes, int n_in,
                              void* d_out, int out_size, void* d_ws, size_t ws_size,
                              hipStream_t stream)
{
    const float* x    = (const float*)d_in[0];
    const float* ea   = (const float*)d_in[1];
    const float* W1   = (const float*)d_in[2];
    const float* as1  = (const float*)d_in[3];
    const float* ad1  = (const float*)d_in[4];
    const float* We1  = (const float*)d_in[5];
    const float* ae1  = (const float*)d_in[6];
    const float* b1   = (const float*)d_in[7];
    const float* g1   = (const float*)d_in[8];
    const float* be1  = (const float*)d_in[9];
    const float* W2   = (const float*)d_in[10];
    const float* as2  = (const float*)d_in[11];
    const float* ad2  = (const float*)d_in[12];
    const float* We2  = (const float*)d_in[13];
    const float* ae2  = (const float*)d_in[14];
    const float* b2   = (const float*)d_in[15];
    const float* g2   = (const float*)d_in[16];
    const float* be2  = (const float*)d_in[17];
    const float* Wlin = (const float*)d_in[18];
    const float* bl   = (const float*)d_in[19];
    const float* gl   = (const float*)d_in[20];
    const float* bel  = (const float*)d_in[21];
    const int*   ei   = (const int*)d_in[22];
    const int*   batch= (const int*)d_in[23];
    float* out = (float*)d_out;

    int N = in_sizes[0] / 128;
    int E = in_sizes[1] / 32;
    int G = out_size / 128;
    const int* srcv = ei;
    const int* dstv = ei + E;

    char* wsb = (char*)d_ws;
    size_t off = 0;
    auto alloc = [&](size_t bytes) -> void* {
        void* p = wsb + off;
        off += (bytes + 15) & ~(size_t)15;
        return p;
    };
    unsigned short* XLb = (unsigned short*)alloc((size_t)N * 128 * 2);
    float* XA     = (float*)alloc((size_t)N * 128 * 4);
    float* elogc  = (float*)alloc((size_t)E * 4);
    float* edot1  = (float*)alloc((size_t)E * 4);
    float* edot2  = (float*)alloc((size_t)E * 4);
    float* als    = (float*)alloc((size_t)N * 4);
    float* ald    = (float*)alloc((size_t)N * 4);
    float* wa     = (float*)alloc(64 * 4);
    float* pooled = (float*)alloc((size_t)G * 128 * 4);
    int*   counts = (int*)alloc((size_t)N * 4);
    int*   local  = (int*)alloc((size_t)N * 4);
    int*   bsums  = (int*)alloc(256 * 4);
    int*   offs   = (int*)alloc((size_t)(N + 1) * 4);
    int*   cursor = (int*)alloc((size_t)N * 4);
    int*   srcc   = (int*)alloc((size_t)E * 4);
    int*   rank   = (int*)alloc((size_t)E * 4);

    int egrid = (E + 255) / 256;
    int ggrid = (N + 31) / 32;
    int agrid = (N + 3) / 4;
    int pgrid = (N + 63) / 64;
    int sgrid = (N + 1023) / 1024;   // scan blocks (<=256 required; N<=262144 ok)
    int ngrid = (N + 255) / 256;

    // CSR build + edge dots (shared by both layers)
    hipMemsetAsync(counts, 0, (size_t)N * 4, stream);
    hipMemsetAsync(pooled, 0, (size_t)G * 128 * 4, stream);
    prep_wa<<<1, 64, 0, stream>>>(We1, ae1, We2, ae2, wa);
    edge_dots<<<egrid, 256, 0, stream>>>(ea, wa, edot1, edot2, E);
    count_edges<<<egrid, 256, 0, stream>>>(dstv, counts, E);
    scan_local<<<sgrid, 256, 0, stream>>>(counts, local, bsums, N);
    scan_bsums<<<1, 256, 0, stream>>>(bsums, sgrid);
    scan_add<<<ngrid, 256, 0, stream>>>(local, bsums, offs, cursor, N, E);
    scatter_edges<<<egrid, 256, 0, stream>>>(srcv, dstv, cursor, srcc, rank, E);

    // layer 1
    gemm_node<<<ggrid, 256, 0, stream>>>(x, W1, as1, ad1, XLb, als, ald, N);
    edge_logits<<<egrid, 256, 0, stream>>>(edot1, srcv, dstv, rank, als, ald, elogc, E);
    aggregate_ln<<<agrid, 256, 0, stream>>>(XLb, elogc, offs, srcc, b1, g1, be1, XA, N);

    // layer 2
    gemm_node<<<ggrid, 256, 0, stream>>>(XA, W2, as2, ad2, XLb, als, ald, N);
    edge_logits<<<egrid, 256, 0, stream>>>(edot2, srcv, dstv, rank, als, ald, elogc, E);
    aggregate_ln<<<agrid, 256, 0, stream>>>(XLb, elogc, offs, srcc, b2, g2, be2, XA, N);

    // pool + head
    pool_partial<<<pgrid, 128, 0, stream>>>(XA, batch, pooled, N);
    pool_head<<<G, 128, 0, stream>>>(pooled, batch, Wlin, bl, gl, bel, out, N);
}

// Round 6
// 407.403 us; speedup vs baseline: 1.9865x; 1.1090x over previous
//
#include <hip/hip_runtime.h>
#include <math.h>

// ---------------------------------------------------------------------------
// Problem shapes: N nodes, D=128 feature dim, ED=32 edge dim, G graphs.
// Accuracy budget: threshold 5.78e-2.  bf16 is used for (a) the gathered XL
// matrix and (b) the node-GEMM inputs (MFMA); everything else fp32.
// ---------------------------------------------------------------------------

typedef __attribute__((ext_vector_type(8))) short bf16x8;
typedef __attribute__((ext_vector_type(4))) float f32x4;

static __device__ __forceinline__ unsigned short f2bf(float f) {
    unsigned u = __float_as_uint(f);
    unsigned r = (u + 0x7fff + ((u >> 16) & 1)) >> 16;   // round-to-nearest-even
    return (unsigned short)r;
}

// Precompute wa = We @ a_e for both layers (each 32 floats).
__global__ __launch_bounds__(64) void prep_wa(
    const float* __restrict__ We1, const float* __restrict__ ae1,
    const float* __restrict__ We2, const float* __restrict__ ae2,
    float* __restrict__ wa /* 64 floats: wa1[0:32], wa2[32:64] */)
{
    int t = threadIdx.x;
    const float* We = (t < 32) ? We1 : We2;
    const float* ae = (t < 32) ? ae1 : ae2;
    int r = t & 31;
    float s = 0.f;
    for (int c = 0; c < 128; c++) s += We[r*128 + c] * ae[c];
    wa[t] = s;
}

// Transpose + bf16-convert both layer weights: WbT[n*128+k] = bf16(W[k*128+n]).
// B-fragments for mfma_16x16x32 then become single contiguous 16B loads.
__global__ __launch_bounds__(256) void prep_wb(
    const float* __restrict__ W1, const float* __restrict__ W2,
    unsigned short* __restrict__ W1bT, unsigned short* __restrict__ W2bT)
{
    int i = blockIdx.x * 256 + threadIdx.x;   // 0..16383
    int k = i >> 7, n = i & 127;
    W1bT[n * 128 + k] = f2bf(W1[i]);
    W2bT[n * 128 + k] = f2bf(W2[i]);
}

// One pass over edge_attr (77 MB): BOTH layers' edge dots + dst-degree count.
__global__ __launch_bounds__(256) void edge_dots_count(
    const float* __restrict__ ea, const float* __restrict__ wa,
    const int* __restrict__ dstv,
    float* __restrict__ edot1, float* __restrict__ edot2,
    int* __restrict__ counts, int E)
{
    int j = blockIdx.x * 256 + threadIdx.x;
    if (j >= E) return;
    const float4* e4 = (const float4*)(ea + (size_t)j * 32);
    float s1 = 0.f, s2 = 0.f;
#pragma unroll
    for (int i = 0; i < 8; i++) {
        float4 v = e4[i];
        float4 w1 = ((const float4*)wa)[i];
        float4 w2 = ((const float4*)(wa + 32))[i];
        s1 += v.x*w1.x + v.y*w1.y + v.z*w1.z + v.w*w1.w;
        s2 += v.x*w2.x + v.y*w2.y + v.z*w2.z + v.w*w2.w;
    }
    edot1[j] = s1; edot2[j] = s2;
    atomicAdd(&counts[dstv[j]], 1);
}

// ---------------------------------------------------------------------------
// MFMA node GEMM: XLb = bf16(X @ W), fused per-row dots with a_src/a_dst.
// 64 rows x 128 cols per 256-thread block (4 waves x 16 rows).  Zero LDS:
// A fragments read from global fp32 and converted in-register; B fragments
// are 16B loads from the bf16-transposed weights (L2-resident, 32 KB).
// Fragment layouts (verified, cdna4 guide): A[m=lane&15][k=quad*8+j],
// B[k=quad*8+j][n=lane&15], D[row=quad*4+reg][col=lane&15].
// ---------------------------------------------------------------------------
__global__ __launch_bounds__(256) void gemm_mfma(
    const float* __restrict__ X, const unsigned short* __restrict__ WbT,
    const float* __restrict__ asrc, const float* __restrict__ adst,
    unsigned short* __restrict__ XLb, float* __restrict__ als, float* __restrict__ ald,
    int nrows)
{
    int t = threadIdx.x;
    int wave = t >> 6;
    int lane = t & 63;
    int l = lane & 15, q = lane >> 4;
    int row0 = blockIdx.x * 64 + wave * 16;

    int arow = row0 + l;                 // row this lane loads for A
    bool avalid = arow < nrows;
    const float* xrow = X + (size_t)arow * 128 + q * 8;

    f32x4 acc[8];
#pragma unroll
    for (int c = 0; c < 8; c++) acc[c] = (f32x4){0.f, 0.f, 0.f, 0.f};

#pragma unroll
    for (int kt = 0; kt < 4; kt++) {
        // A fragment: 8 consecutive fp32 -> 8 bf16
        bf16x8 afrag;
        if (avalid) {
            float4 v0 = *(const float4*)(xrow + kt * 32);
            float4 v1 = *(const float4*)(xrow + kt * 32 + 4);
            afrag[0] = (short)f2bf(v0.x); afrag[1] = (short)f2bf(v0.y);
            afrag[2] = (short)f2bf(v0.z); afrag[3] = (short)f2bf(v0.w);
            afrag[4] = (short)f2bf(v1.x); afrag[5] = (short)f2bf(v1.y);
            afrag[6] = (short)f2bf(v1.z); afrag[7] = (short)f2bf(v1.w);
        } else {
#pragma unroll
            for (int j = 0; j < 8; j++) afrag[j] = 0;
        }
#pragma unroll
        for (int c = 0; c < 8; c++) {
            // B fragment: 16B aligned contiguous load of 8 bf16
            bf16x8 bfrag = *(const bf16x8*)(WbT + (((c * 16 + l) << 7) + kt * 32 + q * 8));
            acc[c] = __builtin_amdgcn_mfma_f32_16x16x32_bf16(afrag, bfrag, acc[c], 0, 0, 0);
        }
    }

    // epilogue: bf16 store + fused attention-logit dots
    float as_[8], ad_[8];
#pragma unroll
    for (int c = 0; c < 8; c++) { as_[c] = asrc[c * 16 + l]; ad_[c] = adst[c * 16 + l]; }

#pragma unroll
    for (int r = 0; r < 4; r++) {
        int row = row0 + q * 4 + r;
        bool valid = row < nrows;
        float ps = 0.f, pd = 0.f;
#pragma unroll
        for (int c = 0; c < 8; c++) {
            float v = acc[c][r];
            if (valid) XLb[(size_t)row * 128 + c * 16 + l] = f2bf(v);
            ps += v * as_[c]; pd += v * ad_[c];
        }
#pragma unroll
        for (int o = 8; o >= 1; o >>= 1) { ps += __shfl_xor(ps, o); pd += __shfl_xor(pd, o); }
        if (l == 0 && valid) { als[row] = ps; ald[row] = pd; }
    }
}

// ---------------------------------------------------------------------------
// Per-edge logits, written directly in CSR order via rank[]:
// elogc[rank[j]] = lrelu(als[src]+ald[dst]+edot[j])
// ---------------------------------------------------------------------------
__global__ __launch_bounds__(256) void edge_logits(
    const float* __restrict__ edot, const int* __restrict__ srcv, const int* __restrict__ dstv,
    const int* __restrict__ rank,
    const float* __restrict__ als, const float* __restrict__ ald,
    float* __restrict__ elogc, int E)
{
    int j = blockIdx.x * 256 + threadIdx.x;
    if (j >= E) return;
    float s = edot[j] + als[srcv[j]] + ald[dstv[j]];
    elogc[rank[j]] = (s >= 0.f) ? s : 0.2f * s;
}

// Hierarchical exclusive scan: 1024 counts per block.
__global__ __launch_bounds__(256) void scan_local(
    const int* __restrict__ counts, int* __restrict__ local,
    int* __restrict__ bsums, int n)
{
    __shared__ int tmp[256];
    int b = blockIdx.x, t = threadIdx.x;
    int base = b * 1024 + t * 4;
    int v0 = 0, v1 = 0, v2 = 0, v3 = 0;
    if (base + 3 < n) {
        const int4 c4 = *(const int4*)(counts + base);
        v0 = c4.x; v1 = c4.y; v2 = c4.z; v3 = c4.w;
    } else {
        if (base + 0 < n) v0 = counts[base + 0];
        if (base + 1 < n) v1 = counts[base + 1];
        if (base + 2 < n) v2 = counts[base + 2];
        if (base + 3 < n) v3 = counts[base + 3];
    }
    tmp[t] = v0 + v1 + v2 + v3; __syncthreads();
    for (int o = 1; o < 256; o <<= 1) {
        int x = (t >= o) ? tmp[t - o] : 0;
        __syncthreads();
        tmp[t] += x;
        __syncthreads();
    }
    int run = (t == 0) ? 0 : tmp[t - 1];
    if (base + 0 < n) { local[base + 0] = run; run += v0; }
    if (base + 1 < n) { local[base + 1] = run; run += v1; }
    if (base + 2 < n) { local[base + 2] = run; run += v2; }
    if (base + 3 < n) { local[base + 3] = run; }
    if (t == 255) bsums[b] = tmp[255];
}

__global__ __launch_bounds__(256) void scan_bsums(int* __restrict__ bsums, int nb)
{
    __shared__ int tmp[256];
    int t = threadIdx.x;
    tmp[t] = (t < nb) ? bsums[t] : 0; __syncthreads();
    for (int o = 1; o < 256; o <<= 1) {
        int x = (t >= o) ? tmp[t - o] : 0;
        __syncthreads();
        tmp[t] += x;
        __syncthreads();
    }
    if (t < nb) bsums[t] = (t == 0) ? 0 : tmp[t - 1];
}

__global__ __launch_bounds__(256) void scan_add(
    const int* __restrict__ local, const int* __restrict__ bsums,
    int* __restrict__ offs, int* __restrict__ cursor, int n, int E)
{
    int i = blockIdx.x * 256 + threadIdx.x;
    if (i < n) {
        int v = local[i] + bsums[i >> 10];
        offs[i] = v; cursor[i] = v;
    }
    if (i == 0) offs[n] = E;
}

// scatter: permute src into CSR order, remember each edge's CSR slot (rank).
__global__ __launch_bounds__(256) void scatter_edges(
    const int* __restrict__ srcv, const int* __restrict__ dstv,
    int* __restrict__ cursor, int* __restrict__ srcc, int* __restrict__ rank, int E)
{
    int j = blockIdx.x * 256 + threadIdx.x;
    if (j < E) {
        int p = atomicAdd(&cursor[dstv[j]], 1);
        srcc[p] = srcv[j];
        rank[j] = p;
    }
}

// ---------------------------------------------------------------------------
// Per-dst-node segment softmax + weighted bf16 row gather + bias + LN.
// One node per 64-lane wave (4/block).  srcc/elogc are CSR-contiguous, so
// all softmax bookkeeping is wave-uniform; row gather unrolled x4 for MLP.
// ---------------------------------------------------------------------------
__global__ __launch_bounds__(256) void aggregate_ln(
    const unsigned short* __restrict__ XLb, const float* __restrict__ elogc,
    const int* __restrict__ offs, const int* __restrict__ srcc,
    const float* __restrict__ bias, const float* __restrict__ gamma, const float* __restrict__ beta,
    float* __restrict__ Xout, int N)
{
    int node = blockIdx.x * 4 + (threadIdx.x >> 6);
    if (node >= N) return;
    int lane = threadIdx.x & 63;
    int lo = offs[node], hi = offs[node + 1];
    int deg = hi - lo;

    // segment max over contiguous elogc[lo:hi)
    float mloc = -3.402823466e38f;
    for (int j = lane; j < deg; j += 64) mloc = fmaxf(mloc, elogc[lo + j]);
#pragma unroll
    for (int o = 32; o >= 1; o >>= 1) mloc = fmaxf(mloc, __shfl_xor(mloc, o));
    float m = mloc;

    const unsigned* rows = (const unsigned*)XLb;   // row s: rows + s*64; lane owns dword `lane`
    float acc0 = 0.f, acc1 = 0.f, ssum = 0.f;      // ssum identical across lanes
    int j = 0;
    for (; j + 4 <= deg; j += 4) {
        int   s0 = srcc[lo + j],     s1 = srcc[lo + j + 1];
        int   s2 = srcc[lo + j + 2], s3 = srcc[lo + j + 3];
        float e0 = elogc[lo + j],     e1 = elogc[lo + j + 1];
        float e2 = elogc[lo + j + 2], e3 = elogc[lo + j + 3];
        unsigned u0 = rows[((size_t)s0 << 6) + lane];
        unsigned u1 = rows[((size_t)s1 << 6) + lane];
        unsigned u2 = rows[((size_t)s2 << 6) + lane];
        unsigned u3 = rows[((size_t)s3 << 6) + lane];
        float w0 = __expf(e0 - m), w1 = __expf(e1 - m);
        float w2 = __expf(e2 - m), w3 = __expf(e3 - m);
        ssum += (w0 + w1) + (w2 + w3);
        acc0 += w0 * __uint_as_float(u0 << 16);
        acc1 += w0 * __uint_as_float(u0 & 0xffff0000u);
        acc0 += w1 * __uint_as_float(u1 << 16);
        acc1 += w1 * __uint_as_float(u1 & 0xffff0000u);
        acc0 += w2 * __uint_as_float(u2 << 16);
        acc1 += w2 * __uint_as_float(u2 & 0xffff0000u);
        acc0 += w3 * __uint_as_float(u3 << 16);
        acc1 += w3 * __uint_as_float(u3 & 0xffff0000u);
    }
    for (; j < deg; j++) {
        int   s0 = srcc[lo + j];
        float w0 = __expf(elogc[lo + j] - m);
        unsigned u0 = rows[((size_t)s0 << 6) + lane];
        ssum += w0;
        acc0 += w0 * __uint_as_float(u0 << 16);
        acc1 += w0 * __uint_as_float(u0 & 0xffff0000u);
    }

    float2 bi = *(const float2*)(bias + 2 * lane);
    float inv = 1.f / (ssum + 1e-16f);
    float y0 = acc0 * inv + bi.x;
    float y1 = acc1 * inv + bi.y;

    // fused LayerNorm over the 128 channels (2 per lane)
    float s = y0 + y1;
#pragma unroll
    for (int o = 32; o >= 1; o >>= 1) s += __shfl_xor(s, o);
    float mean = s * (1.f / 128.f);
    float d0 = y0 - mean, d1 = y1 - mean;
    float v = d0 * d0 + d1 * d1;
#pragma unroll
    for (int o = 32; o >= 1; o >>= 1) v += __shfl_xor(v, o);
    float r = rsqrtf(v * (1.f / 128.f) + 1e-5f);
    float2 ga = *(const float2*)(gamma + 2 * lane);
    float2 be = *(const float2*)(beta  + 2 * lane);
    float2 o2;
    o2.x = d0 * r * ga.x + be.x;
    o2.y = d1 * r * ga.y + be.y;
    *(float2*)(Xout + (size_t)node * 128 + 2 * lane) = o2;
}

// ---------------------------------------------------------------------------
// Pooling phase 1: batch sorted; run-length accumulate, one atomicAdd per
// (graph-run, channel).
// ---------------------------------------------------------------------------
__global__ __launch_bounds__(128) void pool_partial(
    const float* __restrict__ X4, const int* __restrict__ batch,
    float* __restrict__ pooled, int n)
{
    int chunk0 = blockIdx.x * 64;
    if (chunk0 >= n) return;
    int t = threadIdx.x;
    int end = min(chunk0 + 64, n);
    float acc = 0.f;
    int gcur = batch[chunk0];
    for (int r = chunk0; r < end; r++) {
        int g = batch[r];
        if (g != gcur) {
            atomicAdd(&pooled[gcur * 128 + t], acc);
            acc = 0.f; gcur = g;
        }
        acc += X4[(size_t)r * 128 + t];
    }
    atomicAdd(&pooled[gcur * 128 + t], acc);
}

// Pooling phase 2: per-graph mean + final linear + LN + ReLU.
__global__ __launch_bounds__(128) void pool_head(
    const float* __restrict__ pooled, const int* __restrict__ batch,
    const float* __restrict__ Wl, const float* __restrict__ bl,
    const float* __restrict__ gl, const float* __restrict__ bel,
    float* __restrict__ out, int n)
{
    int g = blockIdx.x, t = threadIdx.x;
    int lo = 0, hi = n;
    while (lo < hi) { int mid = (lo + hi) >> 1; if (batch[mid] < g) lo = mid + 1; else hi = mid; }
    int s = lo;
    hi = n;
    while (lo < hi) { int mid = (lo + hi) >> 1; if (batch[mid] < g + 1) lo = mid + 1; else hi = mid; }
    float cntf = (float)(lo - s);

    __shared__ float ps[128];
    __shared__ float red[128];
    ps[t] = pooled[g * 128 + t] / fmaxf(cntf, 1.f);
    __syncthreads();

    float y = bl[t];
    for (int k = 0; k < 128; k++) y += ps[k] * Wl[k * 128 + t];

    red[t] = y; __syncthreads();
#pragma unroll
    for (int o = 64; o >= 1; o >>= 1) { if (t < o) red[t] += red[t + o]; __syncthreads(); }
    float mean = red[0] * (1.f / 128.f); __syncthreads();
    float d = y - mean;
    red[t] = d * d; __syncthreads();
#pragma unroll
    for (int o = 64; o >= 1; o >>= 1) { if (t < o) red[t] += red[t + o]; __syncthreads(); }
    float var = red[0] * (1.f / 128.f);
    float z = d * rsqrtf(var + 1e-5f) * gl[t] + bel[t];
    out[g * 128 + t] = fmaxf(z, 0.f);
}

// ---------------------------------------------------------------------------

extern "C" void kernel_launch(void* const* d_in, const int* in_sizes, int n_in,
                              void* d_out, int out_size, void* d_ws, size_t ws_size,
                              hipStream_t stream)
{
    const float* x    = (const float*)d_in[0];
    const float* ea   = (const float*)d_in[1];
    const float* W1   = (const float*)d_in[2];
    const float* as1  = (const float*)d_in[3];
    const float* ad1  = (const float*)d_in[4];
    const float* We1  = (const float*)d_in[5];
    const float* ae1  = (const float*)d_in[6];
    const float* b1   = (const float*)d_in[7];
    const float* g1   = (const float*)d_in[8];
    const float* be1  = (const float*)d_in[9];
    const float* W2   = (const float*)d_in[10];
    const float* as2  = (const float*)d_in[11];
    const float* ad2  = (const float*)d_in[12];
    const float* We2  = (const float*)d_in[13];
    const float* ae2  = (const float*)d_in[14];
    const float* b2   = (const float*)d_in[15];
    const float* g2   = (const float*)d_in[16];
    const float* be2  = (const float*)d_in[17];
    const float* Wlin = (const float*)d_in[18];
    const float* bl   = (const float*)d_in[19];
    const float* gl   = (const float*)d_in[20];
    const float* bel  = (const float*)d_in[21];
    const int*   ei   = (const int*)d_in[22];
    const int*   batch= (const int*)d_in[23];
    float* out = (float*)d_out;

    int N = in_sizes[0] / 128;
    int E = in_sizes[1] / 32;
    int G = out_size / 128;
    const int* srcv = ei;
    const int* dstv = ei + E;

    char* wsb = (char*)d_ws;
    size_t off = 0;
    auto alloc = [&](size_t bytes) -> void* {
        void* p = wsb + off;
        off += (bytes + 15) & ~(size_t)15;
        return p;
    };
    unsigned short* XLb  = (unsigned short*)alloc((size_t)N * 128 * 2);
    unsigned short* W1bT = (unsigned short*)alloc(16384 * 2);
    unsigned short* W2bT = (unsigned short*)alloc(16384 * 2);
    float* XA     = (float*)alloc((size_t)N * 128 * 4);
    float* elogc  = (float*)alloc((size_t)E * 4);
    float* edot1  = (float*)alloc((size_t)E * 4);
    float* edot2  = (float*)alloc((size_t)E * 4);
    float* als    = (float*)alloc((size_t)N * 4);
    float* ald    = (float*)alloc((size_t)N * 4);
    float* wa     = (float*)alloc(64 * 4);
    float* pooled = (float*)alloc((size_t)G * 128 * 4);
    int*   counts = (int*)alloc((size_t)N * 4);
    int*   local  = (int*)alloc((size_t)N * 4);
    int*   bsums  = (int*)alloc(256 * 4);
    int*   offs   = (int*)alloc((size_t)(N + 1) * 4);
    int*   cursor = (int*)alloc((size_t)N * 4);
    int*   srcc   = (int*)alloc((size_t)E * 4);
    int*   rank   = (int*)alloc((size_t)E * 4);

    int egrid = (E + 255) / 256;
    int mgrid = (N + 63) / 64;       // MFMA gemm blocks (64 rows each)
    int agrid = (N + 3) / 4;
    int pgrid = (N + 63) / 64;
    int sgrid = (N + 1023) / 1024;   // scan blocks (<=256 required; N<=262144 ok)
    int ngrid = (N + 255) / 256;

    // CSR build + edge dots + weight prep (shared by both layers)
    hipMemsetAsync(counts, 0, (size_t)N * 4, stream);
    hipMemsetAsync(pooled, 0, (size_t)G * 128 * 4, stream);
    prep_wa<<<1, 64, 0, stream>>>(We1, ae1, We2, ae2, wa);
    prep_wb<<<64, 256, 0, stream>>>(W1, W2, W1bT, W2bT);
    edge_dots_count<<<egrid, 256, 0, stream>>>(ea, wa, dstv, edot1, edot2, counts, E);
    scan_local<<<sgrid, 256, 0, stream>>>(counts, local, bsums, N);
    scan_bsums<<<1, 256, 0, stream>>>(bsums, sgrid);
    scan_add<<<ngrid, 256, 0, stream>>>(local, bsums, offs, cursor, N, E);
    scatter_edges<<<egrid, 256, 0, stream>>>(srcv, dstv, cursor, srcc, rank, E);

    // layer 1
    gemm_mfma<<<mgrid, 256, 0, stream>>>(x, W1bT, as1, ad1, XLb, als, ald, N);
    edge_logits<<<egrid, 256, 0, stream>>>(edot1, srcv, dstv, rank, als, ald, elogc, E);
    aggregate_ln<<<agrid, 256, 0, stream>>>(XLb, elogc, offs, srcc, b1, g1, be1, XA, N);

    // layer 2
    gemm_mfma<<<mgrid, 256, 0, stream>>>(XA, W2bT, as2, ad2, XLb, als, ald, N);
    edge_logits<<<egrid, 256, 0, stream>>>(edot2, srcv, dstv, rank, als, ald, elogc, E);
    aggregate_ln<<<agrid, 256, 0, stream>>>(XLb, elogc, offs, srcc, b2, g2, be2, XA, N);

    // pool + head
    pool_partial<<<pgrid, 128, 0, stream>>>(XA, batch, pooled, N);
    pool_head<<<G, 128, 0, stream>>>(pooled, batch, Wlin, bl, gl, bel, out, N);
}

// Round 7
// 391.023 us; speedup vs baseline: 2.0697x; 1.0419x over previous
//
#include <hip/hip_runtime.h>
#include <math.h>

// ---------------------------------------------------------------------------
// Problem shapes: N nodes, D=128 feature dim, ED=32 edge dim, G graphs.
// Accuracy budget: threshold 5.78e-2.  bf16 used for: gathered XL, node-GEMM
// inputs (MFMA), and the inter-layer XA activations.  Accumulation fp32.
// ---------------------------------------------------------------------------

typedef __attribute__((ext_vector_type(8))) short bf16x8;
typedef __attribute__((ext_vector_type(4))) float f32x4;

static __device__ __forceinline__ unsigned short f2bf(float f) {
    unsigned u = __float_as_uint(f);
    unsigned r = (u + 0x7fff + ((u >> 16) & 1)) >> 16;   // round-to-nearest-even
    return (unsigned short)r;
}
static __device__ __forceinline__ float bf2f_lo(unsigned u) { return __uint_as_float(u << 16); }
static __device__ __forceinline__ float bf2f_hi(unsigned u) { return __uint_as_float(u & 0xffff0000u); }

// ---------------------------------------------------------------------------
// One prep kernel: blocks 0..63 transpose+bf16 both layer weights
// (WbT[n*128+k] = bf16(W[k*128+n])); block 64 computes wa = We @ a_e for both
// layers (ee @ a_e == edge_attr @ (We @ a_e): [E,128] never materialized).
// ---------------------------------------------------------------------------
__global__ __launch_bounds__(256) void prep_weights(
    const float* __restrict__ W1, const float* __restrict__ W2,
    const float* __restrict__ We1, const float* __restrict__ ae1,
    const float* __restrict__ We2, const float* __restrict__ ae2,
    unsigned short* __restrict__ W1bT, unsigned short* __restrict__ W2bT,
    float* __restrict__ wa /* 64 floats: wa1[0:32], wa2[32:64] */)
{
    int b = blockIdx.x, t = threadIdx.x;
    if (b < 64) {
        int i = b * 256 + t;                 // 0..16383
        int k = i >> 7, n = i & 127;
        W1bT[n * 128 + k] = f2bf(W1[i]);
        W2bT[n * 128 + k] = f2bf(W2[i]);
    } else if (t < 64) {
        const float* We = (t < 32) ? We1 : We2;
        const float* ae = (t < 32) ? ae1 : ae2;
        int r = t & 31;
        float s = 0.f;
        for (int c = 0; c < 128; c++) s += We[r*128 + c] * ae[c];
        wa[t] = s;
    }
}

// One pass over edge_attr (77 MB): BOTH layers' edge dots + dst-degree count.
__global__ __launch_bounds__(256) void edge_dots_count(
    const float* __restrict__ ea, const float* __restrict__ wa,
    const int* __restrict__ dstv,
    float* __restrict__ edot1, float* __restrict__ edot2,
    int* __restrict__ counts, int E)
{
    int j = blockIdx.x * 256 + threadIdx.x;
    if (j >= E) return;
    const float4* e4 = (const float4*)(ea + (size_t)j * 32);
    float s1 = 0.f, s2 = 0.f;
#pragma unroll
    for (int i = 0; i < 8; i++) {
        float4 v = e4[i];
        float4 w1 = ((const float4*)wa)[i];
        float4 w2 = ((const float4*)(wa + 32))[i];
        s1 += v.x*w1.x + v.y*w1.y + v.z*w1.z + v.w*w1.w;
        s2 += v.x*w2.x + v.y*w2.y + v.z*w2.z + v.w*w2.w;
    }
    edot1[j] = s1; edot2[j] = s2;
    atomicAdd(&counts[dstv[j]], 1);
}

// Hierarchical exclusive scan, stage 1: 1024 counts per block.
__global__ __launch_bounds__(256) void scan_local(
    const int* __restrict__ counts, int* __restrict__ local,
    int* __restrict__ bsums, int n)
{
    __shared__ int tmp[256];
    int b = blockIdx.x, t = threadIdx.x;
    int base = b * 1024 + t * 4;
    int v0 = 0, v1 = 0, v2 = 0, v3 = 0;
    if (base + 3 < n) {
        const int4 c4 = *(const int4*)(counts + base);
        v0 = c4.x; v1 = c4.y; v2 = c4.z; v3 = c4.w;
    } else {
        if (base + 0 < n) v0 = counts[base + 0];
        if (base + 1 < n) v1 = counts[base + 1];
        if (base + 2 < n) v2 = counts[base + 2];
        if (base + 3 < n) v3 = counts[base + 3];
    }
    tmp[t] = v0 + v1 + v2 + v3; __syncthreads();
    for (int o = 1; o < 256; o <<= 1) {
        int x = (t >= o) ? tmp[t - o] : 0;
        __syncthreads();
        tmp[t] += x;
        __syncthreads();
    }
    int run = (t == 0) ? 0 : tmp[t - 1];
    if (base + 0 < n) { local[base + 0] = run; run += v0; }
    if (base + 1 < n) { local[base + 1] = run; run += v1; }
    if (base + 2 < n) { local[base + 2] = run; run += v2; }
    if (base + 3 < n) { local[base + 3] = run; }
    if (t == 255) bsums[b] = tmp[255];
}

// Stage 2 (fused): every block redundantly scans the <=256 block sums in LDS,
// then offs[i] = cursor[i] = local[i] + prefix(bsums)[i/1024].
__global__ __launch_bounds__(256) void scan_add(
    const int* __restrict__ local, const int* __restrict__ bsums,
    int* __restrict__ offs, int* __restrict__ cursor, int n, int E, int nb)
{
    __shared__ int tmp[256];
    int t = threadIdx.x;
    tmp[t] = (t < nb) ? bsums[t] : 0; __syncthreads();
    for (int o = 1; o < 256; o <<= 1) {
        int x = (t >= o) ? tmp[t - o] : 0;
        __syncthreads();
        tmp[t] += x;
        __syncthreads();
    }
    int i = blockIdx.x * 256 + t;
    if (i < n) {
        int blk = i >> 10;
        int boff = (blk == 0) ? 0 : tmp[blk - 1];
        int v = local[i] + boff;
        offs[i] = v; cursor[i] = v;
    }
    if (i == 0) offs[n] = E;
}

// scatter: permute src AND both layers' edge dots into CSR order.
__global__ __launch_bounds__(256) void scatter_edges(
    const int* __restrict__ srcv, const int* __restrict__ dstv,
    const float* __restrict__ edot1, const float* __restrict__ edot2,
    int* __restrict__ cursor, int* __restrict__ srcc,
    float* __restrict__ edotc1, float* __restrict__ edotc2, int E)
{
    int j = blockIdx.x * 256 + threadIdx.x;
    if (j < E) {
        int p = atomicAdd(&cursor[dstv[j]], 1);
        srcc[p]   = srcv[j];
        edotc1[p] = edot1[j];
        edotc2[p] = edot2[j];
    }
}

// ---------------------------------------------------------------------------
// MFMA node GEMM: XLb = bf16(X @ W), fused per-row dots with a_src/a_dst.
// 64 rows x 128 cols per 256-thread block (4 waves x 16 rows).  Zero LDS.
// Templated A-path: fp32 input (layer 1) or bf16 input (layer 2, direct 16B).
// Fragment layouts (verified): A[m=lane&15][k=quad*8+j],
// B[k=quad*8+j][n=lane&15], D[row=quad*4+reg][col=lane&15].
// ---------------------------------------------------------------------------
template<bool BF16IN>
__global__ __launch_bounds__(256) void gemm_mfma(
    const void* __restrict__ Xv, const unsigned short* __restrict__ WbT,
    const float* __restrict__ asrc, const float* __restrict__ adst,
    unsigned short* __restrict__ XLb, float* __restrict__ als, float* __restrict__ ald,
    int nrows)
{
    int t = threadIdx.x;
    int wave = t >> 6;
    int lane = t & 63;
    int l = lane & 15, q = lane >> 4;
    int row0 = blockIdx.x * 64 + wave * 16;

    int arow = row0 + l;
    bool avalid = arow < nrows;

    f32x4 acc[8];
#pragma unroll
    for (int c = 0; c < 8; c++) acc[c] = (f32x4){0.f, 0.f, 0.f, 0.f};

#pragma unroll
    for (int kt = 0; kt < 4; kt++) {
        bf16x8 afrag;
        if (avalid) {
            if constexpr (BF16IN) {
                const unsigned short* xrow = (const unsigned short*)Xv + (size_t)arow * 128 + q * 8;
                afrag = *(const bf16x8*)(xrow + kt * 32);
            } else {
                const float* xrow = (const float*)Xv + (size_t)arow * 128 + q * 8;
                float4 v0 = *(const float4*)(xrow + kt * 32);
                float4 v1 = *(const float4*)(xrow + kt * 32 + 4);
                afrag[0] = (short)f2bf(v0.x); afrag[1] = (short)f2bf(v0.y);
                afrag[2] = (short)f2bf(v0.z); afrag[3] = (short)f2bf(v0.w);
                afrag[4] = (short)f2bf(v1.x); afrag[5] = (short)f2bf(v1.y);
                afrag[6] = (short)f2bf(v1.z); afrag[7] = (short)f2bf(v1.w);
            }
        } else {
#pragma unroll
            for (int j = 0; j < 8; j++) afrag[j] = 0;
        }
#pragma unroll
        for (int c = 0; c < 8; c++) {
            bf16x8 bfrag = *(const bf16x8*)(WbT + (((c * 16 + l) << 7) + kt * 32 + q * 8));
            acc[c] = __builtin_amdgcn_mfma_f32_16x16x32_bf16(afrag, bfrag, acc[c], 0, 0, 0);
        }
    }

    float as_[8], ad_[8];
#pragma unroll
    for (int c = 0; c < 8; c++) { as_[c] = asrc[c * 16 + l]; ad_[c] = adst[c * 16 + l]; }

#pragma unroll
    for (int r = 0; r < 4; r++) {
        int row = row0 + q * 4 + r;
        bool valid = row < nrows;
        float ps = 0.f, pd = 0.f;
#pragma unroll
        for (int c = 0; c < 8; c++) {
            float v = acc[c][r];
            if (valid) XLb[(size_t)row * 128 + c * 16 + l] = f2bf(v);
            ps += v * as_[c]; pd += v * ad_[c];
        }
#pragma unroll
        for (int o = 8; o >= 1; o >>= 1) { ps += __shfl_xor(ps, o); pd += __shfl_xor(pd, o); }
        if (l == 0 && valid) { als[row] = ps; ald[row] = pd; }
    }
}

// ---------------------------------------------------------------------------
// Fused per-dst-node: logits (lrelu(als[src]+ald[node]+edotc)) + segment
// softmax + weighted bf16 row gather + bias + LN -> bf16 output.
// One node per 64-lane wave (4/block).  Fast path deg<=64: one edge per lane
// in registers, __shfl broadcasts, gather unrolled x8.  Generic path for
// larger degrees recomputes logits wave-uniformly (correct, rare).
// ---------------------------------------------------------------------------
__global__ __launch_bounds__(256) void aggregate_ln(
    const unsigned short* __restrict__ XLb, const float* __restrict__ edotc,
    const int* __restrict__ offs, const int* __restrict__ srcc,
    const float* __restrict__ als, const float* __restrict__ ald,
    const float* __restrict__ bias, const float* __restrict__ gamma, const float* __restrict__ beta,
    unsigned short* __restrict__ XoutB, int N)
{
    int node = blockIdx.x * 4 + (threadIdx.x >> 6);
    if (node >= N) return;
    int lane = threadIdx.x & 63;
    int lo = offs[node], hi = offs[node + 1];
    int deg = hi - lo;
    float ald_n = ald[node];

    const unsigned* rows = (const unsigned*)XLb;   // row s: rows + s*64
    float acc0 = 0.f, acc1 = 0.f, ssum = 0.f;

    if (deg <= 64) {
        // ---- fast path: one edge per lane ----
        float e_mine = -3.402823466e38f;
        int   s_mine = 0;
        if (lane < deg) {
            int p = lo + lane;
            s_mine = srcc[p];
            float e = edotc[p] + als[s_mine] + ald_n;
            e_mine = (e >= 0.f) ? e : 0.2f * e;
        }
        float m = e_mine;
#pragma unroll
        for (int o = 32; o >= 1; o >>= 1) m = fmaxf(m, __shfl_xor(m, o));

        int j = 0;
        for (; j + 8 <= deg; j += 8) {
            int s0=__shfl(s_mine,j),   s1=__shfl(s_mine,j+1), s2=__shfl(s_mine,j+2), s3=__shfl(s_mine,j+3);
            int s4=__shfl(s_mine,j+4), s5=__shfl(s_mine,j+5), s6=__shfl(s_mine,j+6), s7=__shfl(s_mine,j+7);
            unsigned u0 = rows[((size_t)s0 << 6) + lane];
            unsigned u1 = rows[((size_t)s1 << 6) + lane];
            unsigned u2 = rows[((size_t)s2 << 6) + lane];
            unsigned u3 = rows[((size_t)s3 << 6) + lane];
            unsigned u4 = rows[((size_t)s4 << 6) + lane];
            unsigned u5 = rows[((size_t)s5 << 6) + lane];
            unsigned u6 = rows[((size_t)s6 << 6) + lane];
            unsigned u7 = rows[((size_t)s7 << 6) + lane];
            float w0=__expf(__shfl(e_mine,j)-m),   w1=__expf(__shfl(e_mine,j+1)-m);
            float w2=__expf(__shfl(e_mine,j+2)-m), w3=__expf(__shfl(e_mine,j+3)-m);
            float w4=__expf(__shfl(e_mine,j+4)-m), w5=__expf(__shfl(e_mine,j+5)-m);
            float w6=__expf(__shfl(e_mine,j+6)-m), w7=__expf(__shfl(e_mine,j+7)-m);
            ssum += ((w0+w1)+(w2+w3)) + ((w4+w5)+(w6+w7));
            acc0 += w0*bf2f_lo(u0); acc1 += w0*bf2f_hi(u0);
            acc0 += w1*bf2f_lo(u1); acc1 += w1*bf2f_hi(u1);
            acc0 += w2*bf2f_lo(u2); acc1 += w2*bf2f_hi(u2);
            acc0 += w3*bf2f_lo(u3); acc1 += w3*bf2f_hi(u3);
            acc0 += w4*bf2f_lo(u4); acc1 += w4*bf2f_hi(u4);
            acc0 += w5*bf2f_lo(u5); acc1 += w5*bf2f_hi(u5);
            acc0 += w6*bf2f_lo(u6); acc1 += w6*bf2f_hi(u6);
            acc0 += w7*bf2f_lo(u7); acc1 += w7*bf2f_hi(u7);
        }
        for (; j + 4 <= deg; j += 4) {
            int s0=__shfl(s_mine,j), s1=__shfl(s_mine,j+1), s2=__shfl(s_mine,j+2), s3=__shfl(s_mine,j+3);
            unsigned u0 = rows[((size_t)s0 << 6) + lane];
            unsigned u1 = rows[((size_t)s1 << 6) + lane];
            unsigned u2 = rows[((size_t)s2 << 6) + lane];
            unsigned u3 = rows[((size_t)s3 << 6) + lane];
            float w0=__expf(__shfl(e_mine,j)-m),   w1=__expf(__shfl(e_mine,j+1)-m);
            float w2=__expf(__shfl(e_mine,j+2)-m), w3=__expf(__shfl(e_mine,j+3)-m);
            ssum += (w0+w1)+(w2+w3);
            acc0 += w0*bf2f_lo(u0); acc1 += w0*bf2f_hi(u0);
            acc0 += w1*bf2f_lo(u1); acc1 += w1*bf2f_hi(u1);
            acc0 += w2*bf2f_lo(u2); acc1 += w2*bf2f_hi(u2);
            acc0 += w3*bf2f_lo(u3); acc1 += w3*bf2f_hi(u3);
        }
        for (; j < deg; j++) {
            int s0 = __shfl(s_mine, j);
            float w0 = __expf(__shfl(e_mine, j) - m);
            unsigned u0 = rows[((size_t)s0 << 6) + lane];
            ssum += w0;
            acc0 += w0*bf2f_lo(u0); acc1 += w0*bf2f_hi(u0);
        }
    } else {
        // ---- generic path (rare): strided max, then uniform recompute ----
        float mloc = -3.402823466e38f;
        for (int j = lane; j < deg; j += 64) {
            int p = lo + j;
            float e = edotc[p] + als[srcc[p]] + ald_n;
            e = (e >= 0.f) ? e : 0.2f * e;
            mloc = fmaxf(mloc, e);
        }
#pragma unroll
        for (int o = 32; o >= 1; o >>= 1) mloc = fmaxf(mloc, __shfl_xor(mloc, o));
        float m = mloc;
        for (int j = 0; j < deg; j++) {
            int p = lo + j;
            int s0 = srcc[p];
            float e = edotc[p] + als[s0] + ald_n;
            e = (e >= 0.f) ? e : 0.2f * e;
            float w = __expf(e - m);
            unsigned u0 = rows[((size_t)s0 << 6) + lane];
            ssum += w;
            acc0 += w*bf2f_lo(u0); acc1 += w*bf2f_hi(u0);
        }
    }

    float2 bi = *(const float2*)(bias + 2 * lane);
    float inv = 1.f / (ssum + 1e-16f);
    float y0 = acc0 * inv + bi.x;
    float y1 = acc1 * inv + bi.y;

    // fused LayerNorm over the 128 channels (2 per lane)
    float s = y0 + y1;
#pragma unroll
    for (int o = 32; o >= 1; o >>= 1) s += __shfl_xor(s, o);
    float mean = s * (1.f / 128.f);
    float d0 = y0 - mean, d1 = y1 - mean;
    float v = d0 * d0 + d1 * d1;
#pragma unroll
    for (int o = 32; o >= 1; o >>= 1) v += __shfl_xor(v, o);
    float r = rsqrtf(v * (1.f / 128.f) + 1e-5f);
    float2 ga = *(const float2*)(gamma + 2 * lane);
    float2 be = *(const float2*)(beta  + 2 * lane);
    float o0 = d0 * r * ga.x + be.x;
    float o1 = d1 * r * ga.y + be.y;
    unsigned packed = (unsigned)f2bf(o0) | ((unsigned)f2bf(o1) << 16);
    ((unsigned*)XoutB)[((size_t)node << 6) + lane] = packed;
}

// ---------------------------------------------------------------------------
// Pooling phase 1: batch sorted; run-length accumulate bf16 XA, one atomicAdd
// per (graph-run, channel).
// ---------------------------------------------------------------------------
__global__ __launch_bounds__(128) void pool_partial(
    const unsigned short* __restrict__ XAb, const int* __restrict__ batch,
    float* __restrict__ pooled, int n)
{
    int chunk0 = blockIdx.x * 64;
    if (chunk0 >= n) return;
    int t = threadIdx.x;
    int end = min(chunk0 + 64, n);
    float acc = 0.f;
    int gcur = batch[chunk0];
    for (int r = chunk0; r < end; r++) {
        int g = batch[r];
        if (g != gcur) {
            atomicAdd(&pooled[gcur * 128 + t], acc);
            acc = 0.f; gcur = g;
        }
        acc += __uint_as_float(((unsigned)XAb[(size_t)r * 128 + t]) << 16);
    }
    atomicAdd(&pooled[gcur * 128 + t], acc);
}

// Pooling phase 2: per-graph mean + final linear + LN + ReLU.
__global__ __launch_bounds__(128) void pool_head(
    const float* __restrict__ pooled, const int* __restrict__ batch,
    const float* __restrict__ Wl, const float* __restrict__ bl,
    const float* __restrict__ gl, const float* __restrict__ bel,
    float* __restrict__ out, int n)
{
    int g = blockIdx.x, t = threadIdx.x;
    int lo = 0, hi = n;
    while (lo < hi) { int mid = (lo + hi) >> 1; if (batch[mid] < g) lo = mid + 1; else hi = mid; }
    int s = lo;
    hi = n;
    while (lo < hi) { int mid = (lo + hi) >> 1; if (batch[mid] < g + 1) lo = mid + 1; else hi = mid; }
    float cntf = (float)(lo - s);

    __shared__ float ps[128];
    __shared__ float red[128];
    ps[t] = pooled[g * 128 + t] / fmaxf(cntf, 1.f);
    __syncthreads();

    float y = bl[t];
    for (int k = 0; k < 128; k++) y += ps[k] * Wl[k * 128 + t];

    red[t] = y; __syncthreads();
#pragma unroll
    for (int o = 64; o >= 1; o >>= 1) { if (t < o) red[t] += red[t + o]; __syncthreads(); }
    float mean = red[0] * (1.f / 128.f); __syncthreads();
    float d = y - mean;
    red[t] = d * d; __syncthreads();
#pragma unroll
    for (int o = 64; o >= 1; o >>= 1) { if (t < o) red[t] += red[t + o]; __syncthreads(); }
    float var = red[0] * (1.f / 128.f);
    float z = d * rsqrtf(var + 1e-5f) * gl[t] + bel[t];
    out[g * 128 + t] = fmaxf(z, 0.f);
}

// ---------------------------------------------------------------------------

extern "C" void kernel_launch(void* const* d_in, const int* in_sizes, int n_in,
                              void* d_out, int out_size, void* d_ws, size_t ws_size,
                              hipStream_t stream)
{
    const float* x    = (const float*)d_in[0];
    const float* ea   = (const float*)d_in[1];
    const float* W1   = (const float*)d_in[2];
    const float* as1  = (const float*)d_in[3];
    const float* ad1  = (const float*)d_in[4];
    const float* We1  = (const float*)d_in[5];
    const float* ae1  = (const float*)d_in[6];
    const float* b1   = (const float*)d_in[7];
    const float* g1   = (const float*)d_in[8];
    const float* be1  = (const float*)d_in[9];
    const float* W2   = (const float*)d_in[10];
    const float* as2  = (const float*)d_in[11];
    const float* ad2  = (const float*)d_in[12];
    const float* We2  = (const float*)d_in[13];
    const float* ae2  = (const float*)d_in[14];
    const float* b2   = (const float*)d_in[15];
    const float* g2   = (const float*)d_in[16];
    const float* be2  = (const float*)d_in[17];
    const float* Wlin = (const float*)d_in[18];
    const float* bl   = (const float*)d_in[19];
    const float* gl   = (const float*)d_in[20];
    const float* bel  = (const float*)d_in[21];
    const int*   ei   = (const int*)d_in[22];
    const int*   batch= (const int*)d_in[23];
    float* out = (float*)d_out;

    int N = in_sizes[0] / 128;
    int E = in_sizes[1] / 32;
    int G = out_size / 128;
    const int* srcv = ei;
    const int* dstv = ei + E;

    char* wsb = (char*)d_ws;
    size_t off = 0;
    auto alloc = [&](size_t bytes) -> void* {
        void* p = wsb + off;
        off += (bytes + 15) & ~(size_t)15;
        return p;
    };
    unsigned short* XLb  = (unsigned short*)alloc((size_t)N * 128 * 2);
    unsigned short* XAb  = (unsigned short*)alloc((size_t)N * 128 * 2);
    unsigned short* W1bT = (unsigned short*)alloc(16384 * 2);
    unsigned short* W2bT = (unsigned short*)alloc(16384 * 2);
    float* edot1  = (float*)alloc((size_t)E * 4);
    float* edot2  = (float*)alloc((size_t)E * 4);
    float* edotc1 = (float*)alloc((size_t)E * 4);
    float* edotc2 = (float*)alloc((size_t)E * 4);
    float* als    = (float*)alloc((size_t)N * 4);
    float* ald    = (float*)alloc((size_t)N * 4);
    float* wa     = (float*)alloc(64 * 4);
    float* pooled = (float*)alloc((size_t)G * 128 * 4);
    int*   counts = (int*)alloc((size_t)N * 4);
    int*   local  = (int*)alloc((size_t)N * 4);
    int*   bsums  = (int*)alloc(256 * 4);
    int*   offs   = (int*)alloc((size_t)(N + 1) * 4);
    int*   cursor = (int*)alloc((size_t)N * 4);
    int*   srcc   = (int*)alloc((size_t)E * 4);

    int egrid = (E + 255) / 256;
    int mgrid = (N + 63) / 64;       // MFMA gemm blocks (64 rows each)
    int agrid = (N + 3) / 4;
    int pgrid = (N + 63) / 64;
    int sgrid = (N + 1023) / 1024;   // scan blocks (<=256 required; N<=262144 ok)
    int ngrid = (N + 255) / 256;

    // prep + CSR build + edge dots (shared by both layers)
    hipMemsetAsync(counts, 0, (size_t)N * 4, stream);
    hipMemsetAsync(pooled, 0, (size_t)G * 128 * 4, stream);
    prep_weights<<<65, 256, 0, stream>>>(W1, W2, We1, ae1, We2, ae2, W1bT, W2bT, wa);
    edge_dots_count<<<egrid, 256, 0, stream>>>(ea, wa, dstv, edot1, edot2, counts, E);
    scan_local<<<sgrid, 256, 0, stream>>>(counts, local, bsums, N);
    scan_add<<<ngrid, 256, 0, stream>>>(local, bsums, offs, cursor, N, E, sgrid);
    scatter_edges<<<egrid, 256, 0, stream>>>(srcv, dstv, edot1, edot2, cursor, srcc, edotc1, edotc2, E);

    // layer 1
    gemm_mfma<false><<<mgrid, 256, 0, stream>>>(x, W1bT, as1, ad1, XLb, als, ald, N);
    aggregate_ln<<<agrid, 256, 0, stream>>>(XLb, edotc1, offs, srcc, als, ald, b1, g1, be1, XAb, N);

    // layer 2
    gemm_mfma<true><<<mgrid, 256, 0, stream>>>(XAb, W2bT, as2, ad2, XLb, als, ald, N);
    aggregate_ln<<<agrid, 256, 0, stream>>>(XLb, edotc2, offs, srcc, als, ald, b2, g2, be2, XAb, N);

    // pool + head
    pool_partial<<<pgrid, 128, 0, stream>>>(XAb, batch, pooled, N);
    pool_head<<<G, 128, 0, stream>>>(pooled, batch, Wlin, bl, gl, bel, out, N);
}